// Round 7
// baseline (189.301 us; speedup 1.0000x reference)
//
#include <hip/hip_runtime.h>
#include <hip/hip_bf16.h>
#include <cstdint>
#include <cstddef>

// Problem constants (B,N,M,C2,C1) = (4, 8192, 2048, 256, 128)
static constexpr int BB   = 4;
static constexpr int NN   = 8192;
static constexpr int MM   = 2048;
static constexpr int C1   = 128;
static constexpr int C2   = 256;
static constexpr int CH0  = C2 + C1;   // 384  (K of GEMM0)
static constexpr int O0   = 256;       // out channels layer 0
static constexpr int O1   = 128;       // out channels layer 1
static constexpr int NCOL = BB * NN;   // 32768 columns
static constexpr float BN_EPS = 1e-5f;

// BN-stats super-records (atomicAdd targets; depth <= 16 per address)
// part0: REC0 records of 512 floats {256 sums, 256 sumsqs}  (gemm0, M=256/block)
// part1: REC1 records of 256 floats {128 sums, 128 sumsqs}  (gemm1)
static constexpr int REC0 = 64;
static constexpr int REC1 = 32;

using u16 = unsigned short;
typedef __attribute__((ext_vector_type(8))) short short8;
typedef __attribute__((ext_vector_type(4))) float f32x4;

static __device__ __forceinline__ float bf2f(u16 u) {
    union { unsigned int i; float f; } v; v.i = ((unsigned int)u) << 16; return v.f;
}
static __device__ __forceinline__ u16 f2bf(float f) {
    union { float f; unsigned int i; } v; v.f = f;
    unsigned int r = (v.i + 0x7fffu + ((v.i >> 16) & 1u)) >> 16;
    return (u16)r;
}

// ---------------------------------------------------------------------------
// K1 (fused pre-stage): blocks [0,1024) = 3-NN (r2-proven config: 32 q/block,
// 8 lanes/query, fmaf distance with pre-negated/doubled candidate coords);
// [1024,7680) = transposes + weight casts; [7680,7840) = zero super-records.
__global__ __launch_bounds__(256) void fused_pre_kernel(
        const float* __restrict__ xyz1,  const float* __restrict__ xyz2,
        const float* __restrict__ norm1, const float* __restrict__ norm2,
        int* __restrict__ idxOut, float* __restrict__ wOut,
        const float* __restrict__ points2, u16* __restrict__ p2T,
        const float* __restrict__ points1, u16* __restrict__ p1T,
        const float* __restrict__ W0f, u16* __restrict__ W0b,
        const float* __restrict__ W1f, u16* __restrict__ W1b,
        float* __restrict__ part0, float* __restrict__ part1) {
#pragma clang fp contract(off)
    __shared__ union { float4 pts[1024]; float tile[32][33]; } sm;
    int id = blockIdx.x;
    int t  = threadIdx.x;

    if (id >= 7680) {                       // ---- zero super-records ----
        int flat = (id - 7680) * 256 + t;   // 160*256 = 40960 floats
        if (flat < REC0 * 512) part0[flat] = 0.f;
        else part1[flat - REC0 * 512] = 0.f;
        return;
    }
    if (id >= 1024) {                       // ---- prep: transpose / cast ----
        int pid = id - 1024;
        if (pid < 6144) {
            const float* in; u16* out; int R, C, b, c0, r0;
            if (pid < 2048) {
                in = points2; out = p2T; R = C2; C = MM;
                b = pid >> 9; int rem = pid & 511;
                c0 = (rem & 63) * 32; r0 = (rem >> 6) * 32;
            } else {
                int id2 = pid - 2048;
                in = points1; out = p1T; R = C1; C = NN;
                b = id2 >> 10; int rem = id2 & 1023;
                c0 = (rem & 255) * 32; r0 = (rem >> 8) * 32;
            }
            int tx = t & 31, ty = t >> 5;
            const float* pin = in + (size_t)b * R * C;
            u16* pout = out + (size_t)b * R * C;
#pragma unroll
            for (int j = 0; j < 4; ++j) {
                int r = ty + j * 8;
                sm.tile[r][tx] = pin[(size_t)(r0 + r) * C + (c0 + tx)];
            }
            __syncthreads();
#pragma unroll
            for (int j = 0; j < 4; ++j) {
                int c = ty + j * 8;
                pout[(size_t)(c0 + c) * R + (r0 + tx)] = f2bf(sm.tile[tx][c]);
            }
        } else {
            int i = (pid - 6144) * 256 + t;
            if (i < O0 * CH0) W0b[i] = f2bf(W0f[i]);
            else {
                int i2 = i - O0 * CH0;
                if (i2 < O1 * O0) W1b[i2] = f2bf(W1f[i2]);
            }
        }
        return;
    }

    // ---- 3-NN (exact r2 config) ----
    int b    = id >> 8;                  // 256 blocks of 32 queries per batch
    int nblk = id & 255;
    int j    = t & 7;                    // lane within the 8-thread query group

    int n = nblk * 32 + (t >> 3);
    const float* x1 = xyz1 + (size_t)b * 3 * NN;
    float qx = x1[n], qy = x1[NN + n], qz = x1[2 * NN + n];
    float qq = __builtin_fmaf(qx, qx, __builtin_fmaf(qy, qy, qz * qz));

    const float* x2 = xyz2 + (size_t)b * 3 * MM;

    float d0 = 3.4e38f, d1 = 3.4e38f, d2v = 3.4e38f;
    int   i0 = 0, i1 = 0, i2 = 0;

    for (int chunk = 0; chunk < MM / 1024; ++chunk) {
        __syncthreads();
        for (int i = t; i < 1024; i += 256) {
            int m = chunk * 1024 + i;
            float px = x2[m];
            float py = x2[MM + m];
            float pz = x2[2 * MM + m];
            float pp = __builtin_fmaf(px, px, __builtin_fmaf(py, py, pz * pz));
            // store (-2px, -2py, -2pz, pp): inner loop becomes 3 fma + 1 add
            sm.pts[i] = make_float4(-2.0f * px, -2.0f * py, -2.0f * pz, pp);
        }
        __syncthreads();

#pragma unroll 8
        for (int s = 0; s < 1024 / 8; ++s) {
            int ml = s * 8 + j;          // ascending per thread -> stable ties
            float4 P = sm.pts[ml];
            float d  = __builtin_fmaf(qx, P.x,
                        __builtin_fmaf(qy, P.y,
                         __builtin_fmaf(qz, P.z, qq + P.w)));
            if (d < d2v) {
                int m = chunk * 1024 + ml;
                if (d < d1) {
                    if (d < d0) { d2v = d1; i2 = i1; d1 = d0; i1 = i0; d0 = d; i0 = m; }
                    else        { d2v = d1; i2 = i1; d1 = d;  i1 = m; }
                } else          { d2v = d;  i2 = m; }
            }
        }
    }

    // merge sorted triples across the 8 lanes (lexicographic tie-break)
#pragma unroll
    for (int k = 1; k <= 4; k <<= 1) {
        float e0 = __shfl_xor(d0, k, 64), e1 = __shfl_xor(d1, k, 64), e2 = __shfl_xor(d2v, k, 64);
        int   f0 = __shfl_xor(i0, k, 64), f1 = __shfl_xor(i1, k, 64), f2 = __shfl_xor(i2, k, 64);
        float ed[3] = {e0, e1, e2}; int ef[3] = {f0, f1, f2};
#pragma unroll
        for (int e = 0; e < 3; ++e) {
            float dd = ed[e]; int ff = ef[e];
            bool b2 = (dd < d2v) || (dd == d2v && ff < i2);
            if (b2) {
                bool b1 = (dd < d1) || (dd == d1 && ff < i1);
                if (b1) {
                    d2v = d1; i2 = i1;
                    bool b0 = (dd < d0) || (dd == d0 && ff < i0);
                    if (b0) { d1 = d0; i1 = i0; d0 = dd; i0 = ff; }
                    else    { d1 = dd; i1 = ff; }
                } else { d2v = dd; i2 = ff; }
            }
        }
    }

    if (j == 0) {
        float s0 = sqrtf(fmaxf(d0, 1e-20f));
        float s1 = sqrtf(fmaxf(d1, 1e-20f));
        float s2 = sqrtf(fmaxf(d2v, 1e-20f));
        float r0 = 1.0f / fmaxf(s0, 1e-10f);
        float r1 = 1.0f / fmaxf(s1, 1e-10f);
        float r2 = 1.0f / fmaxf(s2, 1e-10f);
        float rs = (r0 + r1) + r2;
        float w0 = r0 / rs, w1 = r1 / rs, w2 = r2 / rs;

        const float* nm1 = norm1 + (size_t)b * 3 * NN;
        const float* nm2 = norm2 + (size_t)b * 3 * MM;
        float ax = nm1[n], ay = nm1[NN + n], az = nm1[2 * NN + n];
        float nd[3]; int ii[3] = {i0, i1, i2};
#pragma unroll
        for (int k = 0; k < 3; ++k) {
            int ik = ii[k];
            float dx = ax - nm2[ik];
            float dy = ay - nm2[MM + ik];
            float dz = az - nm2[2 * MM + ik];
            nd[k] = sqrtf((dx * dx + dy * dy) + dz * dz);
        }
        float m0 = 1.0f / fmaxf(nd[0], 1e-10f);
        float m1 = 1.0f / fmaxf(nd[1], 1e-10f);
        float m2 = 1.0f / fmaxf(nd[2], 1e-10f);
        float ms = (m0 + m1) + m2;

        int col = b * NN + n;
        idxOut[col * 3 + 0] = i0;
        idxOut[col * 3 + 1] = i1;
        idxOut[col * 3 + 2] = i2;
        wOut[col * 3 + 0] = w0 * (m0 / ms);
        wOut[col * 3 + 1] = w1 * (m1 / ms);
        wOut[col * 3 + 2] = w2 * (m2 / ms);
    }
}

// ---------------------------------------------------------------------------
// K2: materialize interpolated B matrix xI[col][256] (bf16) from p2T + idx/w.
// Streaming gather kernel: no LDS, high occupancy -> gather latency hidden by
// TLP (p2T is 4 MB, L2-resident). Identical arithmetic/rounding to the old
// in-GEMM gather, so B values are bit-identical.
__global__ __launch_bounds__(256) void interp_kernel(
        const u16* __restrict__ p2T,
        const int* __restrict__ idx,
        const float* __restrict__ w,
        u16* __restrict__ xI) {
    int t   = threadIdx.x;
    int col = blockIdx.x * 32 + (t >> 3);    // 1024 blocks x 32 cols
    int kc  = (t & 7) * 32;                  // 32 channels per thread

    int vi0 = idx[col * 3 + 0], vi1 = idx[col * 3 + 1], vi2 = idx[col * 3 + 2];
    float vw0 = w[col * 3 + 0], vw1 = w[col * 3 + 1], vw2 = w[col * 3 + 2];

    const u16* bp  = p2T + (size_t)(col >> 13) * MM * C2 + kc;
    const u16* r0p = bp + (size_t)vi0 * C2;
    const u16* r1p = bp + (size_t)vi1 * C2;
    const u16* r2p = bp + (size_t)vi2 * C2;
    u16* dst = xI + (size_t)col * C2 + kc;

#pragma unroll
    for (int jj = 0; jj < 4; ++jj) {         // 4 x 8 channels
        union { uint4 v; u16 u[8]; } x0, x1, x2, o;
        x0.v = *(const uint4*)(r0p + jj * 8);
        x1.v = *(const uint4*)(r1p + jj * 8);
        x2.v = *(const uint4*)(r2p + jj * 8);
#pragma unroll
        for (int e = 0; e < 8; ++e)
            o.u[e] = f2bf(vw0 * bf2f(x0.u[e]) + vw1 * bf2f(x1.u[e]) + vw2 * bf2f(x2.u[e]));
        *(uint4*)(dst + jj * 8) = o.v;
    }
}

// ---------------------------------------------------------------------------
// K4: GEMM0, merged y-halves, ALL-DMA staging. C^T[col][m] =
// sum_k W0[m][k]*x[col][k] + b0[m], m=0..255 in one block. B comes from xI
// (k<256, contiguous) or p1T (k>=256) via global_load_lds — no gather, no
// VALU in staging. 256 rows x 64 cols, BK=64, 6 K-steps, double-buffered,
// 80 KB LDS -> 2 blocks/CU.
__global__ __launch_bounds__(256, 2) void gemm0_kernel(
        const u16* __restrict__ A,       // W0b (256 x 384)
        const u16* __restrict__ xI,      // interpolated B (NCOL x 256)
        const u16* __restrict__ p1T,
        u16* __restrict__ Ct,            // y0T (col-major, LD = O0)
        const float* __restrict__ bias,  // b0
        float* __restrict__ partials) {  // part0 [REC0][512]
    constexpr int KDIM = CH0;            // 384
    constexpr int COLT = 64;
    constexpr int KT  = KDIM / 64;       // 6
    constexpr int NI  = COLT / 32;       // 2
    constexpr int ASZ = 256 * 64;        // u16 per A buffer (32 KB)
    constexpr int BSZ = COLT * 64;       // u16 per B buffer (8 KB)
    __shared__ u16 smem[2 * ASZ + 2 * BSZ];   // 81920 B

    int t   = threadIdx.x;
    int l   = t & 63;
    int wv  = t >> 6;
    int rl  = l >> 3;                    // staging row-in-group 0..7
    int cg_ = ((l & 7) ^ rl) * 8;        // swizzled global chunk (elements)
    int cb0 = blockIdx.x * COLT;
    int lm  = l & 15;
    int q   = l >> 4;
    int wm0 = (wv & 1) * 64;
    int wn0 = (wv >> 1) * (COLT / 2);

    auto stage = [&](int buf, int k0) {
#pragma unroll
        for (int iss = 0; iss < 8; ++iss) {              // A: 256 rows, DMA
            int row = wv * 64 + iss * 8;
            const u16* g = A + (size_t)(row + rl) * KDIM + k0 + cg_;
            __builtin_amdgcn_global_load_lds(
                (const __attribute__((address_space(1))) unsigned int*)g,
                (__attribute__((address_space(3))) unsigned int*)(&smem[buf * ASZ + row * 64]),
                16, 0, 0);
        }
#pragma unroll
        for (int iss = 0; iss < 2; ++iss) {              // B: 64 cols, DMA
            int row = wv * 16 + iss * 8;
            const u16* g = (k0 < C2)
                ? xI  + (size_t)(cb0 + row + rl) * C2 + k0 + cg_
                : p1T + (size_t)(cb0 + row + rl) * C1 + (k0 - C2) + cg_;
            __builtin_amdgcn_global_load_lds(
                (const __attribute__((address_space(1))) unsigned int*)g,
                (__attribute__((address_space(3))) unsigned int*)(&smem[2 * ASZ + buf * BSZ + row * 64]),
                16, 0, 0);
        }
    };

    f32x4 acc[8][NI] = {};

    stage(0, 0);
    for (int kt = 0; kt < KT; ++kt) {
        __syncthreads();                                  // drains DMA
        if (kt + 1 < KT) stage((kt + 1) & 1, (kt + 1) * 64);
        const u16* As = &smem[(kt & 1) * ASZ];
        const u16* Bs = &smem[2 * ASZ + (kt & 1) * BSZ];
#pragma unroll
        for (int ks = 0; ks < 2; ++ks) {
            int csw = ((ks * 4 + q) ^ (lm & 7)) * 8;      // un-swizzle chunk offset
            short8 av[8], bv[NI];
#pragma unroll
            for (int mi = 0; mi < 8; ++mi) {
                int mrow = (mi >> 2) * 128 + wm0 + (mi & 3) * 16;
                av[mi] = *(const short8*)&As[(mrow + lm) * 64 + csw];
            }
#pragma unroll
            for (int ni = 0; ni < NI; ++ni)
                bv[ni] = *(const short8*)&Bs[(wn0 + ni * 16 + lm) * 64 + csw];
#pragma unroll
            for (int mi = 0; mi < 8; ++mi)
#pragma unroll
                for (int ni = 0; ni < NI; ++ni)
                    acc[mi][ni] = __builtin_amdgcn_mfma_f32_16x16x32_bf16(
                        av[mi], bv[ni], acc[mi][ni], 0, 0, 0);
        }
    }

    // ---- Epilogue (LDS overlay): Cs = 64 x 264 u16, reds = 512 floats ----
    u16*   Cs   = smem;                              // [colL*264 + m], m 0..255
    float* reds = (float*)&smem[COLT * 264];         // {256 sum, 256 sumsq}

    __syncthreads();                                  // all MFMA LDS reads done
    reds[t] = 0.f; reds[256 + t] = 0.f;
    __syncthreads();

#pragma unroll
    for (int mi = 0; mi < 8; ++mi) {
        int chL = (mi >> 2) * 128 + wm0 + (mi & 3) * 16 + q * 4;
        float bv4[4];
#pragma unroll
        for (int r = 0; r < 4; ++r) bv4[r] = bias[chL + r];
        float s[4]  = {0.f, 0.f, 0.f, 0.f};
        float s2[4] = {0.f, 0.f, 0.f, 0.f};
#pragma unroll
        for (int ni = 0; ni < NI; ++ni) {
            int colL = wn0 + ni * 16 + lm;
            union { u16 u[4]; uint2 d; } pk;
#pragma unroll
            for (int r = 0; r < 4; ++r) {
                float v = acc[mi][ni][r] + bv4[r];
                s[r]  += v;
                s2[r] += v * v;
                pk.u[r] = f2bf(v);
            }
            *(uint2*)&Cs[colL * 264 + chL] = pk.d;
        }
#pragma unroll
        for (int r = 0; r < 4; ++r) {
            float a = s[r], b2 = s2[r];
#pragma unroll
            for (int off = 1; off < 16; off <<= 1) {
                a  += __shfl_xor(a, off, 64);
                b2 += __shfl_xor(b2, off, 64);
            }
            if (lm == 0) {
                atomicAdd(&reds[chL + r], a);          // LDS atomic (on-CU)
                atomicAdd(&reds[256 + chL + r], b2);
            }
        }
    }
    __syncthreads();

    // coalesced C-store: 64 cols x 256 m; quarter-rows of 64 u16 = 8 x uint4
    {
        int c = t >> 2, h = t & 3;
        const u16* src = &Cs[c * 264 + h * 64];
        u16* dst = Ct + (size_t)(cb0 + c) * O0 + h * 64;
#pragma unroll
        for (int jj = 0; jj < 8; ++jj)
            *(uint4*)(dst + jj * 8) = *(const uint4*)(src + jj * 8);
    }
    // accumulate block stats into the super-record (depth 8 per address)
    int recIdx = blockIdx.x & (REC0 - 1);
    atomicAdd(&partials[(size_t)recIdx * 512 + t], reds[t]);
    atomicAdd(&partials[(size_t)recIdx * 512 + 256 + t], reds[256 + t]);
}

// ---------------------------------------------------------------------------
// K6: GEMM1 (r2-proven structure): 128 rows x 64 cols, BK=64, fused BN0+ReLU
// on B from part0 super-records ([REC0][512] layout).
__global__ __launch_bounds__(256) void gemm1_kernel(const u16* __restrict__ A,
                                                    const u16* __restrict__ Bt,
                                                    u16* __restrict__ Ct,
                                                    const float* __restrict__ bias,
                                                    const float* __restrict__ redB,
                                                    const float* __restrict__ gB,
                                                    const float* __restrict__ beB,
                                                    float invN,
                                                    float* __restrict__ partials) {
    constexpr int KDIM = O0;             // 256
    constexpr int COLT = 64;
    constexpr int KT  = KDIM / 64;       // 4
    constexpr int NI  = COLT / 32;       // 2
    constexpr int ASZ = 128 * 64;
    constexpr int BSZ = COLT * 64;
    __shared__ u16 smem[2 * ASZ + 2 * BSZ];
    __shared__ float sSc[KDIM];
    __shared__ float sSh[KDIM];

    int t   = threadIdx.x;
    int l   = t & 63;
    int wv  = t >> 6;
    int rl  = l >> 3;
    int cg_ = ((l & 7) ^ rl) * 8;
    int cb0 = blockIdx.x * COLT;
    int lm  = l & 15;
    int q   = l >> 4;
    int wm0 = (wv & 1) * 64;
    int wn0 = (wv >> 1) * (COLT / 2);

    {   // fold BN0 super-record stats into scale/shift (t = channel 0..255)
        float s = 0.f, s2 = 0.f;
#pragma unroll 8
        for (int i = 0; i < REC0; ++i) {
            s  += redB[i * 512 + t];
            s2 += redB[i * 512 + 256 + t];
        }
        float mean = s * invN;
        float var  = fmaxf(s2 * invN - mean * mean, 0.f);
        float inv  = rsqrtf(var + BN_EPS);
        float sc   = gB[t] * inv;
        sSc[t] = sc;
        sSh[t] = beB[t] - mean * sc;
        __syncthreads();
    }

    auto stage = [&](int buf, int k0) {
#pragma unroll
        for (int iss = 0; iss < 4; ++iss) {              // A: 128 rows, DMA
            int row = wv * 32 + iss * 8;
            const u16* g = A + (size_t)(row + rl) * KDIM + k0 + cg_;
            __builtin_amdgcn_global_load_lds(
                (const __attribute__((address_space(1))) unsigned int*)g,
                (__attribute__((address_space(3))) unsigned int*)(&smem[buf * ASZ + row * 64]),
                16, 0, 0);
        }
        {   // B: relu(f*sc+sh) from y0T
            int row = t >> 2;
            int kc  = (t & 3) * 16;
            const u16* gp = Bt + (size_t)(cb0 + row) * KDIM + k0 + kc;
            union { uint4 v; u16 u[8]; } lo, hi;
            lo.v = *(const uint4*)gp;
            hi.v = *(const uint4*)(gp + 8);
#pragma unroll
            for (int e = 0; e < 8; ++e) {
                float f0 = bf2f(lo.u[e]);
                lo.u[e] = f2bf(fmaxf(f0 * sSc[k0 + kc + e] + sSh[k0 + kc + e], 0.f));
                float f1 = bf2f(hi.u[e]);
                hi.u[e] = f2bf(fmaxf(f1 * sSc[k0 + kc + 8 + e] + sSh[k0 + kc + 8 + e], 0.f));
            }
            int c0 = kc >> 3;
            u16* dstB = &smem[2 * ASZ + buf * BSZ + row * 64];
            *(uint4*)&dstB[((c0)     ^ (row & 7)) * 8] = lo.v;
            *(uint4*)&dstB[((c0 + 1) ^ (row & 7)) * 8] = hi.v;
        }
    };

    f32x4 acc[4][NI] = {};

    stage(0, 0);
    for (int kt = 0; kt < KT; ++kt) {
        __syncthreads();
        if (kt + 1 < KT) stage((kt + 1) & 1, (kt + 1) * 64);
        const u16* As = &smem[(kt & 1) * ASZ];
        const u16* Bs = &smem[2 * ASZ + (kt & 1) * BSZ];
#pragma unroll
        for (int ks = 0; ks < 2; ++ks) {
            int csw = ((ks * 4 + q) ^ (lm & 7)) * 8;
            short8 av[4], bv[NI];
#pragma unroll
            for (int mi = 0; mi < 4; ++mi)
                av[mi] = *(const short8*)&As[(wm0 + mi * 16 + lm) * 64 + csw];
#pragma unroll
            for (int ni = 0; ni < NI; ++ni)
                bv[ni] = *(const short8*)&Bs[(wn0 + ni * 16 + lm) * 64 + csw];
#pragma unroll
            for (int mi = 0; mi < 4; ++mi)
#pragma unroll
                for (int ni = 0; ni < NI; ++ni)
                    acc[mi][ni] = __builtin_amdgcn_mfma_f32_16x16x32_bf16(
                        av[mi], bv[ni], acc[mi][ni], 0, 0, 0);
        }
    }

    // ---- Epilogue (LDS overlay): Cs = 64 x 136 u16, reds = 256 floats ----
    u16*   Cs   = smem;
    float* reds = (float*)&smem[COLT * 136];

    __syncthreads();
    if (t < 256) reds[t] = 0.f;
    __syncthreads();

#pragma unroll
    for (int mi = 0; mi < 4; ++mi) {
        int chL = wm0 + mi * 16 + q * 4;
        float bv4[4];
#pragma unroll
        for (int r = 0; r < 4; ++r) bv4[r] = bias[chL + r];
        float s[4]  = {0.f, 0.f, 0.f, 0.f};
        float s2[4] = {0.f, 0.f, 0.f, 0.f};
#pragma unroll
        for (int ni = 0; ni < NI; ++ni) {
            int colL = wn0 + ni * 16 + lm;
            union { u16 u[4]; uint2 d; } pk;
#pragma unroll
            for (int r = 0; r < 4; ++r) {
                float v = acc[mi][ni][r] + bv4[r];
                s[r]  += v;
                s2[r] += v * v;
                pk.u[r] = f2bf(v);
            }
            *(uint2*)&Cs[colL * 136 + chL] = pk.d;
        }
#pragma unroll
        for (int r = 0; r < 4; ++r) {
            float a = s[r], b2 = s2[r];
#pragma unroll
            for (int off = 1; off < 16; off <<= 1) {
                a  += __shfl_xor(a, off, 64);
                b2 += __shfl_xor(b2, off, 64);
            }
            if (lm == 0) {
                atomicAdd(&reds[chL + r], a);
                atomicAdd(&reds[128 + chL + r], b2);
            }
        }
    }
    __syncthreads();

    for (int u = t; u < COLT * 2; u += 256) {
        int c = u >> 1, h = u & 1;
        const u16* src = &Cs[c * 136 + h * 64];
        u16* dst = Ct + (size_t)(cb0 + c) * O1 + h * 64;
#pragma unroll
        for (int jj = 0; jj < 8; ++jj)
            *(uint4*)(dst + jj * 8) = *(const uint4*)(src + jj * 8);
    }
    int recIdx = blockIdx.x & (REC1 - 1);
    atomicAdd(&partials[(size_t)recIdx * 256 + t], reds[t]);
}

// ---------------------------------------------------------------------------
// K8: final BN+ReLU on y1^T[col][c] (bf16) and transpose to out[b][c][n] (f32).
__global__ __launch_bounds__(256) void finalize_kernel(const u16* __restrict__ y1T,
                                                       const float* __restrict__ part1,
                                                       const float* __restrict__ g1,
                                                       const float* __restrict__ be1,
                                                       float invN,
                                                       float* __restrict__ out) {
    __shared__ float tile[64][129];
    __shared__ float sc[O1], sh[O1];
    int t  = threadIdx.x;
    int b  = blockIdx.y;
    int n0 = blockIdx.x * 64;

    if (t < O1) {
        float s = 0.f, s2 = 0.f;
#pragma unroll 8
        for (int i = 0; i < REC1; ++i) {
            s  += part1[i * 256 + t];
            s2 += part1[i * 256 + 128 + t];
        }
        float mean = s * invN;
        float var  = fmaxf(s2 * invN - mean * mean, 0.f);
        float inv  = rsqrtf(var + BN_EPS);
        float scv  = g1[t] * inv;
        sc[t] = scv;
        sh[t] = be1[t] - mean * scv;
    }
    __syncthreads();

#pragma unroll
    for (int it = 0; it < 32; ++it) {
        int flat = it * 256 + t;
        int cl = flat >> 7;          // local col 0..63
        int c  = flat & 127;
        int col = b * NN + n0 + cl;
        float v = bf2f(y1T[(size_t)col * O1 + c]);
        tile[cl][c] = fmaxf(v * sc[c] + sh[c], 0.f);
    }
    __syncthreads();
#pragma unroll
    for (int it = 0; it < 32; ++it) {
        int flat = it * 256 + t;
        int c  = flat >> 6;          // channel 0..127
        int nl = flat & 63;
        out[(size_t)b * O1 * NN + (size_t)c * NN + n0 + nl] = tile[nl][c];
    }
}

// ---------------------------------------------------------------------------
extern "C" void kernel_launch(void* const* d_in, const int* in_sizes, int n_in,
                              void* d_out, int out_size, void* d_ws, size_t ws_size,
                              hipStream_t stream) {
    (void)in_sizes; (void)n_in; (void)out_size; (void)ws_size;

    const float* xyz1    = (const float*)d_in[0];
    const float* xyz2    = (const float*)d_in[1];
    const float* norm1   = (const float*)d_in[2];
    const float* norm2   = (const float*)d_in[3];
    const float* points1 = (const float*)d_in[4];
    const float* points2 = (const float*)d_in[5];
    const float* W0f     = (const float*)d_in[6];
    const float* b0      = (const float*)d_in[7];
    const float* g0      = (const float*)d_in[8];
    const float* be0     = (const float*)d_in[9];
    const float* W1f     = (const float*)d_in[10];
    const float* b1      = (const float*)d_in[11];
    const float* g1      = (const float*)d_in[12];
    const float* be1     = (const float*)d_in[13];
    float* out = (float*)d_out;

    // workspace carve-up (all 256B-aligned)
    char* w8 = (char*)d_ws;
    size_t off = 0;
    auto carve = [&](size_t bytes) { void* p = w8 + off; off += (bytes + 255) & ~(size_t)255; return p; };
    int*   idxW   = (int*)  carve((size_t)NCOL * 3 * sizeof(int));
    float* wW     = (float*)carve((size_t)NCOL * 3 * sizeof(float));
    u16*   p2T    = (u16*)  carve((size_t)BB * MM * C2 * 2);
    u16*   p1T    = (u16*)  carve((size_t)BB * NN * C1 * 2);
    u16*   W0b    = (u16*)  carve((size_t)O0 * CH0 * 2);
    u16*   W1b    = (u16*)  carve((size_t)O1 * O0 * 2);
    u16*   y0T    = (u16*)  carve((size_t)NCOL * O0 * 2);
    u16*   xI     = (u16*)  carve((size_t)NCOL * C2 * 2);   // 16.8 MB
    float* part0  = (float*)carve((size_t)REC0 * 512 * sizeof(float));  // 128 KB
    float* part1  = (float*)carve((size_t)REC1 * 256 * sizeof(float));  // 32 KB
    // y1T aliases xI: xI is consumed by gemm0 before gemm1 writes y1T
    u16*   y1T    = xI;

    const float invN = 1.0f / (float)NCOL;

    // 1024 3-NN blocks + 6656 prep blocks + 160 zero blocks
    fused_pre_kernel<<<7840, 256, 0, stream>>>(
        xyz1, xyz2, norm1, norm2, idxW, wW,
        points2, p2T, points1, p1T, W0f, W0b, W1f, W1b, part0, part1);

    // materialize interpolated B (gather off the GEMM critical path)
    interp_kernel<<<NCOL / 32, 256, 0, stream>>>(p2T, idxW, wW, xI);

    // GEMM0 (merged y-halves, all-DMA staging)
    gemm0_kernel<<<NCOL / 64, 256, 0, stream>>>(
        W0b, xI, p1T, y0T, b0, part0);

    // GEMM1: fused BN0+ReLU on B; prologue folds part0+g0/be0
    gemm1_kernel<<<NCOL / 64, 256, 0, stream>>>(
        W1b, y0T, y1T, b1, part0, g0, be0, invN, part1);

    finalize_kernel<<<dim3(NN / 64, BB), 256, 0, stream>>>(y1T, part1, g1, be1, invN, out);
}

// Round 8
// 182.218 us; speedup vs baseline: 1.0389x; 1.0389x over previous
//
#include <hip/hip_runtime.h>
#include <hip/hip_bf16.h>
#include <cstdint>
#include <cstddef>

// Problem constants (B,N,M,C2,C1) = (4, 8192, 2048, 256, 128)
static constexpr int BB   = 4;
static constexpr int NN   = 8192;
static constexpr int MM   = 2048;
static constexpr int C1   = 128;
static constexpr int C2   = 256;
static constexpr int CH0  = C2 + C1;   // 384  (K of GEMM0)
static constexpr int O0   = 256;       // out channels layer 0
static constexpr int O1   = 128;       // out channels layer 1
static constexpr int NCOL = BB * NN;   // 32768 columns
static constexpr float BN_EPS = 1e-5f;

// BN-stats super-records (atomicAdd targets; depth <= 16 per address)
// part0: REC0 records of 512 floats {256 sums, 256 sumsqs}  (gemm0, M=256/block)
// part1: REC1 records of 256 floats {128 sums, 128 sumsqs}  (gemm1)
static constexpr int REC0 = 64;
static constexpr int REC1 = 32;

using u16 = unsigned short;
typedef __attribute__((ext_vector_type(8))) short short8;
typedef __attribute__((ext_vector_type(4))) float f32x4;

static __device__ __forceinline__ float bf2f(u16 u) {
    union { unsigned int i; float f; } v; v.i = ((unsigned int)u) << 16; return v.f;
}
static __device__ __forceinline__ u16 f2bf(float f) {
    union { float f; unsigned int i; } v; v.f = f;
    unsigned int r = (v.i + 0x7fffu + ((v.i >> 16) & 1u)) >> 16;
    return (u16)r;
}

// ---------------------------------------------------------------------------
// K1 (fused pre-stage): blocks [0,1024) = 3-NN (r2-proven config: 32 q/block,
// 8 lanes/query, fmaf distance with pre-negated/doubled candidate coords);
// [1024,7680) = transposes + weight casts; [7680,7840) = zero super-records.
__global__ __launch_bounds__(256) void fused_pre_kernel(
        const float* __restrict__ xyz1,  const float* __restrict__ xyz2,
        const float* __restrict__ norm1, const float* __restrict__ norm2,
        int* __restrict__ idxOut, float* __restrict__ wOut,
        const float* __restrict__ points2, u16* __restrict__ p2T,
        const float* __restrict__ points1, u16* __restrict__ p1T,
        const float* __restrict__ W0f, u16* __restrict__ W0b,
        const float* __restrict__ W1f, u16* __restrict__ W1b,
        float* __restrict__ part0, float* __restrict__ part1) {
#pragma clang fp contract(off)
    __shared__ union { float4 pts[1024]; float tile[32][33]; } sm;
    int id = blockIdx.x;
    int t  = threadIdx.x;

    if (id >= 7680) {                       // ---- zero super-records ----
        int flat = (id - 7680) * 256 + t;   // 160*256 = 40960 floats
        if (flat < REC0 * 512) part0[flat] = 0.f;
        else part1[flat - REC0 * 512] = 0.f;
        return;
    }
    if (id >= 1024) {                       // ---- prep: transpose / cast ----
        int pid = id - 1024;
        if (pid < 6144) {
            const float* in; u16* out; int R, C, b, c0, r0;
            if (pid < 2048) {
                in = points2; out = p2T; R = C2; C = MM;
                b = pid >> 9; int rem = pid & 511;
                c0 = (rem & 63) * 32; r0 = (rem >> 6) * 32;
            } else {
                int id2 = pid - 2048;
                in = points1; out = p1T; R = C1; C = NN;
                b = id2 >> 10; int rem = id2 & 1023;
                c0 = (rem & 255) * 32; r0 = (rem >> 8) * 32;
            }
            int tx = t & 31, ty = t >> 5;
            const float* pin = in + (size_t)b * R * C;
            u16* pout = out + (size_t)b * R * C;
#pragma unroll
            for (int j = 0; j < 4; ++j) {
                int r = ty + j * 8;
                sm.tile[r][tx] = pin[(size_t)(r0 + r) * C + (c0 + tx)];
            }
            __syncthreads();
#pragma unroll
            for (int j = 0; j < 4; ++j) {
                int c = ty + j * 8;
                pout[(size_t)(c0 + c) * R + (r0 + tx)] = f2bf(sm.tile[tx][c]);
            }
        } else {
            int i = (pid - 6144) * 256 + t;
            if (i < O0 * CH0) W0b[i] = f2bf(W0f[i]);
            else {
                int i2 = i - O0 * CH0;
                if (i2 < O1 * O0) W1b[i2] = f2bf(W1f[i2]);
            }
        }
        return;
    }

    // ---- 3-NN (exact r2 config) ----
    int b    = id >> 8;                  // 256 blocks of 32 queries per batch
    int nblk = id & 255;
    int j    = t & 7;                    // lane within the 8-thread query group

    int n = nblk * 32 + (t >> 3);
    const float* x1 = xyz1 + (size_t)b * 3 * NN;
    float qx = x1[n], qy = x1[NN + n], qz = x1[2 * NN + n];
    float qq = __builtin_fmaf(qx, qx, __builtin_fmaf(qy, qy, qz * qz));

    const float* x2 = xyz2 + (size_t)b * 3 * MM;

    float d0 = 3.4e38f, d1 = 3.4e38f, d2v = 3.4e38f;
    int   i0 = 0, i1 = 0, i2 = 0;

    for (int chunk = 0; chunk < MM / 1024; ++chunk) {
        __syncthreads();
        for (int i = t; i < 1024; i += 256) {
            int m = chunk * 1024 + i;
            float px = x2[m];
            float py = x2[MM + m];
            float pz = x2[2 * MM + m];
            float pp = __builtin_fmaf(px, px, __builtin_fmaf(py, py, pz * pz));
            // store (-2px, -2py, -2pz, pp): inner loop becomes 3 fma + 1 add
            sm.pts[i] = make_float4(-2.0f * px, -2.0f * py, -2.0f * pz, pp);
        }
        __syncthreads();

#pragma unroll 8
        for (int s = 0; s < 1024 / 8; ++s) {
            int ml = s * 8 + j;          // ascending per thread -> stable ties
            float4 P = sm.pts[ml];
            float d  = __builtin_fmaf(qx, P.x,
                        __builtin_fmaf(qy, P.y,
                         __builtin_fmaf(qz, P.z, qq + P.w)));
            if (d < d2v) {
                int m = chunk * 1024 + ml;
                if (d < d1) {
                    if (d < d0) { d2v = d1; i2 = i1; d1 = d0; i1 = i0; d0 = d; i0 = m; }
                    else        { d2v = d1; i2 = i1; d1 = d;  i1 = m; }
                } else          { d2v = d;  i2 = m; }
            }
        }
    }

    // merge sorted triples across the 8 lanes (lexicographic tie-break)
#pragma unroll
    for (int k = 1; k <= 4; k <<= 1) {
        float e0 = __shfl_xor(d0, k, 64), e1 = __shfl_xor(d1, k, 64), e2 = __shfl_xor(d2v, k, 64);
        int   f0 = __shfl_xor(i0, k, 64), f1 = __shfl_xor(i1, k, 64), f2 = __shfl_xor(i2, k, 64);
        float ed[3] = {e0, e1, e2}; int ef[3] = {f0, f1, f2};
#pragma unroll
        for (int e = 0; e < 3; ++e) {
            float dd = ed[e]; int ff = ef[e];
            bool b2 = (dd < d2v) || (dd == d2v && ff < i2);
            if (b2) {
                bool b1 = (dd < d1) || (dd == d1 && ff < i1);
                if (b1) {
                    d2v = d1; i2 = i1;
                    bool b0 = (dd < d0) || (dd == d0 && ff < i0);
                    if (b0) { d1 = d0; i1 = i0; d0 = dd; i0 = ff; }
                    else    { d1 = dd; i1 = ff; }
                } else { d2v = dd; i2 = ff; }
            }
        }
    }

    if (j == 0) {
        float s0 = sqrtf(fmaxf(d0, 1e-20f));
        float s1 = sqrtf(fmaxf(d1, 1e-20f));
        float s2 = sqrtf(fmaxf(d2v, 1e-20f));
        float r0 = 1.0f / fmaxf(s0, 1e-10f);
        float r1 = 1.0f / fmaxf(s1, 1e-10f);
        float r2 = 1.0f / fmaxf(s2, 1e-10f);
        float rs = (r0 + r1) + r2;
        float w0 = r0 / rs, w1 = r1 / rs, w2 = r2 / rs;

        const float* nm1 = norm1 + (size_t)b * 3 * NN;
        const float* nm2 = norm2 + (size_t)b * 3 * MM;
        float ax = nm1[n], ay = nm1[NN + n], az = nm1[2 * NN + n];
        float nd[3]; int ii[3] = {i0, i1, i2};
#pragma unroll
        for (int k = 0; k < 3; ++k) {
            int ik = ii[k];
            float dx = ax - nm2[ik];
            float dy = ay - nm2[MM + ik];
            float dz = az - nm2[2 * MM + ik];
            nd[k] = sqrtf((dx * dx + dy * dy) + dz * dz);
        }
        float m0 = 1.0f / fmaxf(nd[0], 1e-10f);
        float m1 = 1.0f / fmaxf(nd[1], 1e-10f);
        float m2 = 1.0f / fmaxf(nd[2], 1e-10f);
        float ms = (m0 + m1) + m2;

        int col = b * NN + n;
        idxOut[col * 3 + 0] = i0;
        idxOut[col * 3 + 1] = i1;
        idxOut[col * 3 + 2] = i2;
        wOut[col * 3 + 0] = w0 * (m0 / ms);
        wOut[col * 3 + 1] = w1 * (m1 / ms);
        wOut[col * 3 + 2] = w2 * (m2 / ms);
    }
}

// ---------------------------------------------------------------------------
// K4: GEMM0, merged y-halves, T14 async-STAGE split: B-gather loads issued
// BEFORE the MFMA phase (latency hides under compute), interp+ds_write AFTER.
// A via global_load_lds (drained by end-of-iter barrier -> also hidden).
// 256 rows x 64 cols, BK=64, 6 K-steps, 80 KB LDS -> 2 blocks/CU.
__global__ __launch_bounds__(256, 2) void gemm0_kernel(
        const u16* __restrict__ A,       // W0b (256 x 384)
        const u16* __restrict__ Bt,      // p2T
        const u16* __restrict__ p1T,
        const int* __restrict__ idx,
        const float* __restrict__ w,
        u16* __restrict__ Ct,            // y0T (col-major, LD = O0)
        const float* __restrict__ bias,  // b0
        float* __restrict__ partials) {  // part0 [REC0][512]
    constexpr int KDIM = CH0;            // 384
    constexpr int COLT = 64;
    constexpr int KT  = KDIM / 64;       // 6
    constexpr int NI  = COLT / 32;       // 2
    constexpr int ASZ = 256 * 64;        // u16 per A buffer (32 KB)
    constexpr int BSZ = COLT * 64;       // u16 per B buffer (8 KB)
    __shared__ u16 smem[2 * ASZ + 2 * BSZ];   // 81920 B

    int t   = threadIdx.x;
    int l   = t & 63;
    int wv  = t >> 6;
    int rl  = l >> 3;                    // staging row-in-group 0..7
    int cg_ = ((l & 7) ^ rl) * 8;        // swizzled global chunk (elements)
    int cb0 = blockIdx.x * COLT;
    int lm  = l & 15;
    int q   = l >> 4;
    int wm0 = (wv & 1) * 64;
    int wn0 = (wv >> 1) * (COLT / 2);

    // per-thread column interpolation params
    int colg = cb0 + (t >> 2);
    int vi0 = idx[colg * 3 + 0], vi1 = idx[colg * 3 + 1], vi2 = idx[colg * 3 + 2];
    float vw0 = w[colg * 3 + 0], vw1 = w[colg * 3 + 1], vw2 = w[colg * 3 + 2];
    const u16* p2base = Bt + (size_t)(cb0 >> 13) * MM * C2;
    int brow = t >> 2;                   // 0..63
    int bkc  = (t & 3) * 16;

    uint4 bl[6];                         // in-flight gather regs (24 VGPR)
    auto loadB = [&](int k0) {           // ISSUE ONLY — no wait here
        const u16* bp  = p2base + k0 + bkc;
        const u16* r0p = bp + (size_t)vi0 * C2;
        const u16* r1p = bp + (size_t)vi1 * C2;
        const u16* r2p = bp + (size_t)vi2 * C2;
        bl[0] = *(const uint4*)r0p; bl[1] = *(const uint4*)(r0p + 8);
        bl[2] = *(const uint4*)r1p; bl[3] = *(const uint4*)(r1p + 8);
        bl[4] = *(const uint4*)r2p; bl[5] = *(const uint4*)(r2p + 8);
    };
    auto writeB = [&](int buf) {         // interp + swizzled LDS store (waits vmcnt)
        union U { uint4 v; u16 u[8]; } x0, y0, x1, y1, x2, y2, lo, hi;
        x0.v = bl[0]; y0.v = bl[1];
        x1.v = bl[2]; y1.v = bl[3];
        x2.v = bl[4]; y2.v = bl[5];
#pragma unroll
        for (int e = 0; e < 8; ++e) {
            lo.u[e] = f2bf(vw0 * bf2f(x0.u[e]) + vw1 * bf2f(x1.u[e]) + vw2 * bf2f(x2.u[e]));
            hi.u[e] = f2bf(vw0 * bf2f(y0.u[e]) + vw1 * bf2f(y1.u[e]) + vw2 * bf2f(y2.u[e]));
        }
        int c0 = bkc >> 3;
        u16* dstB = &smem[2 * ASZ + buf * BSZ + brow * 64];
        *(uint4*)&dstB[((c0)     ^ (brow & 7)) * 8] = lo.v;
        *(uint4*)&dstB[((c0 + 1) ^ (brow & 7)) * 8] = hi.v;
    };
    auto stageA = [&](int buf, int k0) {
#pragma unroll
        for (int iss = 0; iss < 8; ++iss) {              // A: 256 rows, DMA
            int row = wv * 64 + iss * 8;
            const u16* g = A + (size_t)(row + rl) * KDIM + k0 + cg_;
            __builtin_amdgcn_global_load_lds(
                (const __attribute__((address_space(1))) unsigned int*)g,
                (__attribute__((address_space(3))) unsigned int*)(&smem[buf * ASZ + row * 64]),
                16, 0, 0);
        }
    };
    auto stageBdma = [&](int buf, int k0) {              // p1T DMA (K-contig)
#pragma unroll
        for (int iss = 0; iss < 2; ++iss) {
            int row = wv * 16 + iss * 8;
            const u16* g = p1T + (size_t)(cb0 + row + rl) * C1 + (k0 - C2) + cg_;
            __builtin_amdgcn_global_load_lds(
                (const __attribute__((address_space(1))) unsigned int*)g,
                (__attribute__((address_space(3))) unsigned int*)(&smem[2 * ASZ + buf * BSZ + row * 64]),
                16, 0, 0);
        }
    };

    f32x4 acc[8][NI] = {};

    // prologue: tile 0 (exposed once)
    loadB(0);
    stageA(0, 0);
    writeB(0);
    __syncthreads();

    for (int kt = 0; kt < KT; ++kt) {
        int nk = kt + 1;
        if (nk < KT) {                                    // issue next tile early
            stageA(nk & 1, nk * 64);
            if (nk * 64 < C2) loadB(nk * 64);
            else              stageBdma(nk & 1, nk * 64);
        }
        const u16* As = &smem[(kt & 1) * ASZ];
        const u16* Bs = &smem[2 * ASZ + (kt & 1) * BSZ];
#pragma unroll
        for (int ks = 0; ks < 2; ++ks) {
            int csw = ((ks * 4 + q) ^ (lm & 7)) * 8;      // un-swizzle chunk offset
            short8 av[8], bv[NI];
#pragma unroll
            for (int mi = 0; mi < 8; ++mi) {
                int mrow = (mi >> 2) * 128 + wm0 + (mi & 3) * 16;
                av[mi] = *(const short8*)&As[(mrow + lm) * 64 + csw];
            }
#pragma unroll
            for (int ni = 0; ni < NI; ++ni)
                bv[ni] = *(const short8*)&Bs[(wn0 + ni * 16 + lm) * 64 + csw];
#pragma unroll
            for (int mi = 0; mi < 8; ++mi)
#pragma unroll
                for (int ni = 0; ni < NI; ++ni)
                    acc[mi][ni] = __builtin_amdgcn_mfma_f32_16x16x32_bf16(
                        av[mi], bv[ni], acc[mi][ni], 0, 0, 0);
        }
        if (nk < KT) {
            if (nk * 64 < C2) writeB(nk & 1);             // vmcnt hidden by MFMA
            __syncthreads();                              // tile nk ready for all
        }
    }

    // ---- Epilogue (LDS overlay): Cs = 64 x 264 u16, reds = 512 floats ----
    u16*   Cs   = smem;                              // [colL*264 + m], m 0..255
    float* reds = (float*)&smem[COLT * 264];         // {256 sum, 256 sumsq}

    __syncthreads();                                  // all MFMA LDS reads done
    reds[t] = 0.f; reds[256 + t] = 0.f;
    __syncthreads();

#pragma unroll
    for (int mi = 0; mi < 8; ++mi) {
        int chL = (mi >> 2) * 128 + wm0 + (mi & 3) * 16 + q * 4;
        float bv4[4];
#pragma unroll
        for (int r = 0; r < 4; ++r) bv4[r] = bias[chL + r];
        float s[4]  = {0.f, 0.f, 0.f, 0.f};
        float s2[4] = {0.f, 0.f, 0.f, 0.f};
#pragma unroll
        for (int ni = 0; ni < NI; ++ni) {
            int colL = wn0 + ni * 16 + lm;
            union { u16 u[4]; uint2 d; } pk;
#pragma unroll
            for (int r = 0; r < 4; ++r) {
                float v = acc[mi][ni][r] + bv4[r];
                s[r]  += v;
                s2[r] += v * v;
                pk.u[r] = f2bf(v);
            }
            *(uint2*)&Cs[colL * 264 + chL] = pk.d;
        }
#pragma unroll
        for (int r = 0; r < 4; ++r) {
            float a = s[r], b2 = s2[r];
#pragma unroll
            for (int off = 1; off < 16; off <<= 1) {
                a  += __shfl_xor(a, off, 64);
                b2 += __shfl_xor(b2, off, 64);
            }
            if (lm == 0) {
                atomicAdd(&reds[chL + r], a);          // LDS atomic (on-CU)
                atomicAdd(&reds[256 + chL + r], b2);
            }
        }
    }
    __syncthreads();

    // coalesced C-store: 64 cols x 256 m; quarter-rows of 64 u16 = 8 x uint4
    {
        int c = t >> 2, h = t & 3;
        const u16* src = &Cs[c * 264 + h * 64];
        u16* dst = Ct + (size_t)(cb0 + c) * O0 + h * 64;
#pragma unroll
        for (int jj = 0; jj < 8; ++jj)
            *(uint4*)(dst + jj * 8) = *(const uint4*)(src + jj * 8);
    }
    // accumulate block stats into the super-record (depth 8 per address)
    int recIdx = blockIdx.x & (REC0 - 1);
    atomicAdd(&partials[(size_t)recIdx * 512 + t], reds[t]);
    atomicAdd(&partials[(size_t)recIdx * 512 + 256 + t], reds[256 + t]);
}

// ---------------------------------------------------------------------------
// K6: GEMM1 with the same T14 split: y0T loads issued before MFMA, BN0+ReLU
// + ds_write after. 128 rows x 64 cols, BK=64, part0 [REC0][512] layout.
__global__ __launch_bounds__(256) void gemm1_kernel(const u16* __restrict__ A,
                                                    const u16* __restrict__ Bt,
                                                    u16* __restrict__ Ct,
                                                    const float* __restrict__ bias,
                                                    const float* __restrict__ redB,
                                                    const float* __restrict__ gB,
                                                    const float* __restrict__ beB,
                                                    float invN,
                                                    float* __restrict__ partials) {
    constexpr int KDIM = O0;             // 256
    constexpr int COLT = 64;
    constexpr int KT  = KDIM / 64;       // 4
    constexpr int NI  = COLT / 32;       // 2
    constexpr int ASZ = 128 * 64;
    constexpr int BSZ = COLT * 64;
    __shared__ u16 smem[2 * ASZ + 2 * BSZ];
    __shared__ float sSc[KDIM];
    __shared__ float sSh[KDIM];

    int t   = threadIdx.x;
    int l   = t & 63;
    int wv  = t >> 6;
    int rl  = l >> 3;
    int cg_ = ((l & 7) ^ rl) * 8;
    int cb0 = blockIdx.x * COLT;
    int lm  = l & 15;
    int q   = l >> 4;
    int wm0 = (wv & 1) * 64;
    int wn0 = (wv >> 1) * (COLT / 2);
    int brow = t >> 2;                   // 0..63
    int bkc  = (t & 3) * 16;

    {   // fold BN0 super-record stats into scale/shift (t = channel 0..255)
        float s = 0.f, s2 = 0.f;
#pragma unroll 8
        for (int i = 0; i < REC0; ++i) {
            s  += redB[i * 512 + t];
            s2 += redB[i * 512 + 256 + t];
        }
        float mean = s * invN;
        float var  = fmaxf(s2 * invN - mean * mean, 0.f);
        float inv  = rsqrtf(var + BN_EPS);
        float sc   = gB[t] * inv;
        sSc[t] = sc;
        sSh[t] = beB[t] - mean * sc;
        __syncthreads();
    }

    uint4 bl0, bl1;                      // in-flight y0T regs
    auto loadB = [&](int k0) {
        const u16* gp = Bt + (size_t)(cb0 + brow) * KDIM + k0 + bkc;
        bl0 = *(const uint4*)gp;
        bl1 = *(const uint4*)(gp + 8);
    };
    auto writeB = [&](int buf, int k0) { // relu(f*sc+sh) + swizzled LDS store
        union U { uint4 v; u16 u[8]; } lo, hi;
        lo.v = bl0; hi.v = bl1;
#pragma unroll
        for (int e = 0; e < 8; ++e) {
            float f0 = bf2f(lo.u[e]);
            lo.u[e] = f2bf(fmaxf(f0 * sSc[k0 + bkc + e] + sSh[k0 + bkc + e], 0.f));
            float f1 = bf2f(hi.u[e]);
            hi.u[e] = f2bf(fmaxf(f1 * sSc[k0 + bkc + 8 + e] + sSh[k0 + bkc + 8 + e], 0.f));
        }
        int c0 = bkc >> 3;
        u16* dstB = &smem[2 * ASZ + buf * BSZ + brow * 64];
        *(uint4*)&dstB[((c0)     ^ (brow & 7)) * 8] = lo.v;
        *(uint4*)&dstB[((c0 + 1) ^ (brow & 7)) * 8] = hi.v;
    };
    auto stageA = [&](int buf, int k0) {
#pragma unroll
        for (int iss = 0; iss < 4; ++iss) {              // A: 128 rows, DMA
            int row = wv * 32 + iss * 8;
            const u16* g = A + (size_t)(row + rl) * KDIM + k0 + cg_;
            __builtin_amdgcn_global_load_lds(
                (const __attribute__((address_space(1))) unsigned int*)g,
                (__attribute__((address_space(3))) unsigned int*)(&smem[buf * ASZ + row * 64]),
                16, 0, 0);
        }
    };

    f32x4 acc[4][NI] = {};

    // prologue: tile 0 (exposed once)
    loadB(0);
    stageA(0, 0);
    writeB(0, 0);
    __syncthreads();

    for (int kt = 0; kt < KT; ++kt) {
        int nk = kt + 1;
        if (nk < KT) {
            stageA(nk & 1, nk * 64);
            loadB(nk * 64);
        }
        const u16* As = &smem[(kt & 1) * ASZ];
        const u16* Bs = &smem[2 * ASZ + (kt & 1) * BSZ];
#pragma unroll
        for (int ks = 0; ks < 2; ++ks) {
            int csw = ((ks * 4 + q) ^ (lm & 7)) * 8;
            short8 av[4], bv[NI];
#pragma unroll
            for (int mi = 0; mi < 4; ++mi)
                av[mi] = *(const short8*)&As[(wm0 + mi * 16 + lm) * 64 + csw];
#pragma unroll
            for (int ni = 0; ni < NI; ++ni)
                bv[ni] = *(const short8*)&Bs[(wn0 + ni * 16 + lm) * 64 + csw];
#pragma unroll
            for (int mi = 0; mi < 4; ++mi)
#pragma unroll
                for (int ni = 0; ni < NI; ++ni)
                    acc[mi][ni] = __builtin_amdgcn_mfma_f32_16x16x32_bf16(
                        av[mi], bv[ni], acc[mi][ni], 0, 0, 0);
        }
        if (nk < KT) {
            writeB(nk & 1, nk * 64);                      // vmcnt hidden by MFMA
            __syncthreads();
        }
    }

    // ---- Epilogue (LDS overlay): Cs = 64 x 136 u16, reds = 256 floats ----
    u16*   Cs   = smem;
    float* reds = (float*)&smem[COLT * 136];

    __syncthreads();
    if (t < 256) reds[t] = 0.f;
    __syncthreads();

#pragma unroll
    for (int mi = 0; mi < 4; ++mi) {
        int chL = wm0 + mi * 16 + q * 4;
        float bv4[4];
#pragma unroll
        for (int r = 0; r < 4; ++r) bv4[r] = bias[chL + r];
        float s[4]  = {0.f, 0.f, 0.f, 0.f};
        float s2[4] = {0.f, 0.f, 0.f, 0.f};
#pragma unroll
        for (int ni = 0; ni < NI; ++ni) {
            int colL = wn0 + ni * 16 + lm;
            union { u16 u[4]; uint2 d; } pk;
#pragma unroll
            for (int r = 0; r < 4; ++r) {
                float v = acc[mi][ni][r] + bv4[r];
                s[r]  += v;
                s2[r] += v * v;
                pk.u[r] = f2bf(v);
            }
            *(uint2*)&Cs[colL * 136 + chL] = pk.d;
        }
#pragma unroll
        for (int r = 0; r < 4; ++r) {
            float a = s[r], b2 = s2[r];
#pragma unroll
            for (int off = 1; off < 16; off <<= 1) {
                a  += __shfl_xor(a, off, 64);
                b2 += __shfl_xor(b2, off, 64);
            }
            if (lm == 0) {
                atomicAdd(&reds[chL + r], a);
                atomicAdd(&reds[128 + chL + r], b2);
            }
        }
    }
    __syncthreads();

    for (int u = t; u < COLT * 2; u += 256) {
        int c = u >> 1, h = u & 1;
        const u16* src = &Cs[c * 136 + h * 64];
        u16* dst = Ct + (size_t)(cb0 + c) * O1 + h * 64;
#pragma unroll
        for (int jj = 0; jj < 8; ++jj)
            *(uint4*)(dst + jj * 8) = *(const uint4*)(src + jj * 8);
    }
    int recIdx = blockIdx.x & (REC1 - 1);
    atomicAdd(&partials[(size_t)recIdx * 256 + t], reds[t]);
}

// ---------------------------------------------------------------------------
// K8: final BN+ReLU on y1^T[col][c] (bf16) and transpose to out[b][c][n] (f32).
__global__ __launch_bounds__(256) void finalize_kernel(const u16* __restrict__ y1T,
                                                       const float* __restrict__ part1,
                                                       const float* __restrict__ g1,
                                                       const float* __restrict__ be1,
                                                       float invN,
                                                       float* __restrict__ out) {
    __shared__ float tile[64][129];
    __shared__ float sc[O1], sh[O1];
    int t  = threadIdx.x;
    int b  = blockIdx.y;
    int n0 = blockIdx.x * 64;

    if (t < O1) {
        float s = 0.f, s2 = 0.f;
#pragma unroll 8
        for (int i = 0; i < REC1; ++i) {
            s  += part1[i * 256 + t];
            s2 += part1[i * 256 + 128 + t];
        }
        float mean = s * invN;
        float var  = fmaxf(s2 * invN - mean * mean, 0.f);
        float inv  = rsqrtf(var + BN_EPS);
        float scv  = g1[t] * inv;
        sc[t] = scv;
        sh[t] = be1[t] - mean * scv;
    }
    __syncthreads();

#pragma unroll
    for (int it = 0; it < 32; ++it) {
        int flat = it * 256 + t;
        int cl = flat >> 7;          // local col 0..63
        int c  = flat & 127;
        int col = b * NN + n0 + cl;
        float v = bf2f(y1T[(size_t)col * O1 + c]);
        tile[cl][c] = fmaxf(v * sc[c] + sh[c], 0.f);
    }
    __syncthreads();
#pragma unroll
    for (int it = 0; it < 32; ++it) {
        int flat = it * 256 + t;
        int c  = flat >> 6;          // channel 0..127
        int nl = flat & 63;
        out[(size_t)b * O1 * NN + (size_t)c * NN + n0 + nl] = tile[nl][c];
    }
}

// ---------------------------------------------------------------------------
extern "C" void kernel_launch(void* const* d_in, const int* in_sizes, int n_in,
                              void* d_out, int out_size, void* d_ws, size_t ws_size,
                              hipStream_t stream) {
    (void)in_sizes; (void)n_in; (void)out_size; (void)ws_size;

    const float* xyz1    = (const float*)d_in[0];
    const float* xyz2    = (const float*)d_in[1];
    const float* norm1   = (const float*)d_in[2];
    const float* norm2   = (const float*)d_in[3];
    const float* points1 = (const float*)d_in[4];
    const float* points2 = (const float*)d_in[5];
    const float* W0f     = (const float*)d_in[6];
    const float* b0      = (const float*)d_in[7];
    const float* g0      = (const float*)d_in[8];
    const float* be0     = (const float*)d_in[9];
    const float* W1f     = (const float*)d_in[10];
    const float* b1      = (const float*)d_in[11];
    const float* g1      = (const float*)d_in[12];
    const float* be1     = (const float*)d_in[13];
    float* out = (float*)d_out;

    // workspace carve-up (all 256B-aligned)
    char* w8 = (char*)d_ws;
    size_t off = 0;
    auto carve = [&](size_t bytes) { void* p = w8 + off; off += (bytes + 255) & ~(size_t)255; return p; };
    int*   idxW   = (int*)  carve((size_t)NCOL * 3 * sizeof(int));
    float* wW     = (float*)carve((size_t)NCOL * 3 * sizeof(float));
    u16*   p2T    = (u16*)  carve((size_t)BB * MM * C2 * 2);
    u16*   p1T    = (u16*)  carve((size_t)BB * NN * C1 * 2);
    u16*   W0b    = (u16*)  carve((size_t)O0 * CH0 * 2);
    u16*   W1b    = (u16*)  carve((size_t)O1 * O0 * 2);
    u16*   y0T    = (u16*)  carve((size_t)NCOL * O0 * 2);
    u16*   y1T    = (u16*)  carve((size_t)NCOL * O1 * 2);
    float* part0  = (float*)carve((size_t)REC0 * 512 * sizeof(float));  // 128 KB
    float* part1  = (float*)carve((size_t)REC1 * 256 * sizeof(float));  // 32 KB

    const float invN = 1.0f / (float)NCOL;

    // 1024 3-NN blocks + 6656 prep blocks + 160 zero blocks
    fused_pre_kernel<<<7840, 256, 0, stream>>>(
        xyz1, xyz2, norm1, norm2, idxW, wW,
        points2, p2T, points1, p1T, W0f, W0b, W1f, W1b, part0, part1);

    // GEMM0 (merged y-halves, T14 async-STAGE split)
    gemm0_kernel<<<NCOL / 64, 256, 0, stream>>>(
        W0b, p2T, p1T, idxW, wW, y0T, b0, part0);

    // GEMM1 (T14 split): fused BN0+ReLU on B; prologue folds part0+g0/be0
    gemm1_kernel<<<NCOL / 64, 256, 0, stream>>>(
        W1b, y0T, y1T, b1, part0, g0, be0, invN, part1);

    finalize_kernel<<<dim3(NN / 64, BB), 256, 0, stream>>>(y1T, part1, g1, be1, invN, out);
}

// Round 9
// 181.136 us; speedup vs baseline: 1.0451x; 1.0060x over previous
//
#include <hip/hip_runtime.h>
#include <hip/hip_bf16.h>
#include <cstdint>
#include <cstddef>

// Problem constants (B,N,M,C2,C1) = (4, 8192, 2048, 256, 128)
static constexpr int BB   = 4;
static constexpr int NN   = 8192;
static constexpr int MM   = 2048;
static constexpr int C1   = 128;
static constexpr int C2   = 256;
static constexpr int CH0  = C2 + C1;   // 384  (K of GEMM0)
static constexpr int O0   = 256;       // out channels layer 0
static constexpr int O1   = 128;       // out channels layer 1
static constexpr int NCOL = BB * NN;   // 32768 columns
static constexpr float BN_EPS = 1e-5f;

// BN-stats super-records (atomicAdd targets; depth <= 16 per address)
// part0: REC0 records of 512 floats {256 sums, 256 sumsqs}  (gemm0, M=256/block)
// part1: REC1 records of 256 floats {128 sums, 128 sumsqs}  (gemm1)
static constexpr int REC0 = 64;
static constexpr int REC1 = 32;

using u16 = unsigned short;
typedef __attribute__((ext_vector_type(8))) short short8;
typedef __attribute__((ext_vector_type(4))) float f32x4;

static __device__ __forceinline__ float bf2f(u16 u) {
    union { unsigned int i; float f; } v; v.i = ((unsigned int)u) << 16; return v.f;
}
static __device__ __forceinline__ u16 f2bf(float f) {
    union { float f; unsigned int i; } v; v.f = f;
    unsigned int r = (v.i + 0x7fffu + ((v.i >> 16) & 1u)) >> 16;
    return (u16)r;
}

// ---------------------------------------------------------------------------
// K1 (fused pre-stage): blocks [0,1024) = 3-NN (r2-proven config: 32 q/block,
// 8 lanes/query, fmaf distance with pre-negated/doubled candidate coords);
// [1024,7680) = transposes + weight casts; [7680,7840) = zero super-records.
__global__ __launch_bounds__(256) void fused_pre_kernel(
        const float* __restrict__ xyz1,  const float* __restrict__ xyz2,
        const float* __restrict__ norm1, const float* __restrict__ norm2,
        int* __restrict__ idxOut, float* __restrict__ wOut,
        const float* __restrict__ points2, u16* __restrict__ p2T,
        const float* __restrict__ points1, u16* __restrict__ p1T,
        const float* __restrict__ W0f, u16* __restrict__ W0b,
        const float* __restrict__ W1f, u16* __restrict__ W1b,
        float* __restrict__ part0, float* __restrict__ part1) {
#pragma clang fp contract(off)
    __shared__ union { float4 pts[1024]; float tile[32][33]; } sm;
    int id = blockIdx.x;
    int t  = threadIdx.x;

    if (id >= 7680) {                       // ---- zero super-records ----
        int flat = (id - 7680) * 256 + t;   // 160*256 = 40960 floats
        if (flat < REC0 * 512) part0[flat] = 0.f;
        else part1[flat - REC0 * 512] = 0.f;
        return;
    }
    if (id >= 1024) {                       // ---- prep: transpose / cast ----
        int pid = id - 1024;
        if (pid < 6144) {
            const float* in; u16* out; int R, C, b, c0, r0;
            if (pid < 2048) {
                in = points2; out = p2T; R = C2; C = MM;
                b = pid >> 9; int rem = pid & 511;
                c0 = (rem & 63) * 32; r0 = (rem >> 6) * 32;
            } else {
                int id2 = pid - 2048;
                in = points1; out = p1T; R = C1; C = NN;
                b = id2 >> 10; int rem = id2 & 1023;
                c0 = (rem & 255) * 32; r0 = (rem >> 8) * 32;
            }
            int tx = t & 31, ty = t >> 5;
            const float* pin = in + (size_t)b * R * C;
            u16* pout = out + (size_t)b * R * C;
#pragma unroll
            for (int j = 0; j < 4; ++j) {
                int r = ty + j * 8;
                sm.tile[r][tx] = pin[(size_t)(r0 + r) * C + (c0 + tx)];
            }
            __syncthreads();
#pragma unroll
            for (int j = 0; j < 4; ++j) {
                int c = ty + j * 8;
                pout[(size_t)(c0 + c) * R + (r0 + tx)] = f2bf(sm.tile[tx][c]);
            }
        } else {
            int i = (pid - 6144) * 256 + t;
            if (i < O0 * CH0) W0b[i] = f2bf(W0f[i]);
            else {
                int i2 = i - O0 * CH0;
                if (i2 < O1 * O0) W1b[i2] = f2bf(W1f[i2]);
            }
        }
        return;
    }

    // ---- 3-NN (exact r2 config) ----
    int b    = id >> 8;                  // 256 blocks of 32 queries per batch
    int nblk = id & 255;
    int j    = t & 7;                    // lane within the 8-thread query group

    int n = nblk * 32 + (t >> 3);
    const float* x1 = xyz1 + (size_t)b * 3 * NN;
    float qx = x1[n], qy = x1[NN + n], qz = x1[2 * NN + n];
    float qq = __builtin_fmaf(qx, qx, __builtin_fmaf(qy, qy, qz * qz));

    const float* x2 = xyz2 + (size_t)b * 3 * MM;

    float d0 = 3.4e38f, d1 = 3.4e38f, d2v = 3.4e38f;
    int   i0 = 0, i1 = 0, i2 = 0;

    for (int chunk = 0; chunk < MM / 1024; ++chunk) {
        __syncthreads();
        for (int i = t; i < 1024; i += 256) {
            int m = chunk * 1024 + i;
            float px = x2[m];
            float py = x2[MM + m];
            float pz = x2[2 * MM + m];
            float pp = __builtin_fmaf(px, px, __builtin_fmaf(py, py, pz * pz));
            // store (-2px, -2py, -2pz, pp): inner loop becomes 3 fma + 1 add
            sm.pts[i] = make_float4(-2.0f * px, -2.0f * py, -2.0f * pz, pp);
        }
        __syncthreads();

#pragma unroll 8
        for (int s = 0; s < 1024 / 8; ++s) {
            int ml = s * 8 + j;          // ascending per thread -> stable ties
            float4 P = sm.pts[ml];
            float d  = __builtin_fmaf(qx, P.x,
                        __builtin_fmaf(qy, P.y,
                         __builtin_fmaf(qz, P.z, qq + P.w)));
            if (d < d2v) {
                int m = chunk * 1024 + ml;
                if (d < d1) {
                    if (d < d0) { d2v = d1; i2 = i1; d1 = d0; i1 = i0; d0 = d; i0 = m; }
                    else        { d2v = d1; i2 = i1; d1 = d;  i1 = m; }
                } else          { d2v = d;  i2 = m; }
            }
        }
    }

    // merge sorted triples across the 8 lanes (lexicographic tie-break)
#pragma unroll
    for (int k = 1; k <= 4; k <<= 1) {
        float e0 = __shfl_xor(d0, k, 64), e1 = __shfl_xor(d1, k, 64), e2 = __shfl_xor(d2v, k, 64);
        int   f0 = __shfl_xor(i0, k, 64), f1 = __shfl_xor(i1, k, 64), f2 = __shfl_xor(i2, k, 64);
        float ed[3] = {e0, e1, e2}; int ef[3] = {f0, f1, f2};
#pragma unroll
        for (int e = 0; e < 3; ++e) {
            float dd = ed[e]; int ff = ef[e];
            bool b2 = (dd < d2v) || (dd == d2v && ff < i2);
            if (b2) {
                bool b1 = (dd < d1) || (dd == d1 && ff < i1);
                if (b1) {
                    d2v = d1; i2 = i1;
                    bool b0 = (dd < d0) || (dd == d0 && ff < i0);
                    if (b0) { d1 = d0; i1 = i0; d0 = dd; i0 = ff; }
                    else    { d1 = dd; i1 = ff; }
                } else { d2v = dd; i2 = ff; }
            }
        }
    }

    if (j == 0) {
        float s0 = sqrtf(fmaxf(d0, 1e-20f));
        float s1 = sqrtf(fmaxf(d1, 1e-20f));
        float s2 = sqrtf(fmaxf(d2v, 1e-20f));
        float r0 = 1.0f / fmaxf(s0, 1e-10f);
        float r1 = 1.0f / fmaxf(s1, 1e-10f);
        float r2 = 1.0f / fmaxf(s2, 1e-10f);
        float rs = (r0 + r1) + r2;
        float w0 = r0 / rs, w1 = r1 / rs, w2 = r2 / rs;

        const float* nm1 = norm1 + (size_t)b * 3 * NN;
        const float* nm2 = norm2 + (size_t)b * 3 * MM;
        float ax = nm1[n], ay = nm1[NN + n], az = nm1[2 * NN + n];
        float nd[3]; int ii[3] = {i0, i1, i2};
#pragma unroll
        for (int k = 0; k < 3; ++k) {
            int ik = ii[k];
            float dx = ax - nm2[ik];
            float dy = ay - nm2[MM + ik];
            float dz = az - nm2[2 * MM + ik];
            nd[k] = sqrtf((dx * dx + dy * dy) + dz * dz);
        }
        float m0 = 1.0f / fmaxf(nd[0], 1e-10f);
        float m1 = 1.0f / fmaxf(nd[1], 1e-10f);
        float m2 = 1.0f / fmaxf(nd[2], 1e-10f);
        float ms = (m0 + m1) + m2;

        int col = b * NN + n;
        idxOut[col * 3 + 0] = i0;
        idxOut[col * 3 + 1] = i1;
        idxOut[col * 3 + 2] = i2;
        wOut[col * 3 + 0] = w0 * (m0 / ms);
        wOut[col * 3 + 1] = w1 * (m1 / ms);
        wOut[col * 3 + 2] = w2 * (m2 / ms);
    }
}

// ---------------------------------------------------------------------------
// K4: GEMM0, merged y-halves, T14 async-STAGE split: B-gather loads issued
// BEFORE the MFMA phase (latency hides under compute), interp+ds_write AFTER.
// A via global_load_lds (drained by end-of-iter barrier -> also hidden).
// 256 rows x 64 cols, BK=64, 6 K-steps, 80 KB LDS -> 2 blocks/CU.
__global__ __launch_bounds__(256, 2) void gemm0_kernel(
        const u16* __restrict__ A,       // W0b (256 x 384)
        const u16* __restrict__ Bt,      // p2T
        const u16* __restrict__ p1T,
        const int* __restrict__ idx,
        const float* __restrict__ w,
        u16* __restrict__ Ct,            // y0T (col-major, LD = O0)
        const float* __restrict__ bias,  // b0
        float* __restrict__ partials) {  // part0 [REC0][512]
    constexpr int KDIM = CH0;            // 384
    constexpr int COLT = 64;
    constexpr int KT  = KDIM / 64;       // 6
    constexpr int NI  = COLT / 32;       // 2
    constexpr int ASZ = 256 * 64;        // u16 per A buffer (32 KB)
    constexpr int BSZ = COLT * 64;       // u16 per B buffer (8 KB)
    __shared__ u16 smem[2 * ASZ + 2 * BSZ];   // 81920 B

    int t   = threadIdx.x;
    int l   = t & 63;
    int wv  = t >> 6;
    int rl  = l >> 3;                    // staging row-in-group 0..7
    int cg_ = ((l & 7) ^ rl) * 8;        // swizzled global chunk (elements)
    int cb0 = blockIdx.x * COLT;
    int lm  = l & 15;
    int q   = l >> 4;
    int wm0 = (wv & 1) * 64;
    int wn0 = (wv >> 1) * (COLT / 2);

    // per-thread column interpolation params
    int colg = cb0 + (t >> 2);
    int vi0 = idx[colg * 3 + 0], vi1 = idx[colg * 3 + 1], vi2 = idx[colg * 3 + 2];
    float vw0 = w[colg * 3 + 0], vw1 = w[colg * 3 + 1], vw2 = w[colg * 3 + 2];
    const u16* p2base = Bt + (size_t)(cb0 >> 13) * MM * C2;
    int brow = t >> 2;                   // 0..63
    int bkc  = (t & 3) * 16;

    uint4 bl[6];                         // in-flight gather regs (24 VGPR)
    auto loadB = [&](int k0) {           // ISSUE ONLY — no wait here
        const u16* bp  = p2base + k0 + bkc;
        const u16* r0p = bp + (size_t)vi0 * C2;
        const u16* r1p = bp + (size_t)vi1 * C2;
        const u16* r2p = bp + (size_t)vi2 * C2;
        bl[0] = *(const uint4*)r0p; bl[1] = *(const uint4*)(r0p + 8);
        bl[2] = *(const uint4*)r1p; bl[3] = *(const uint4*)(r1p + 8);
        bl[4] = *(const uint4*)r2p; bl[5] = *(const uint4*)(r2p + 8);
    };
    auto writeB = [&](int buf) {         // interp + swizzled LDS store (waits vmcnt)
        union U { uint4 v; u16 u[8]; } x0, y0, x1, y1, x2, y2, lo, hi;
        x0.v = bl[0]; y0.v = bl[1];
        x1.v = bl[2]; y1.v = bl[3];
        x2.v = bl[4]; y2.v = bl[5];
#pragma unroll
        for (int e = 0; e < 8; ++e) {
            lo.u[e] = f2bf(vw0 * bf2f(x0.u[e]) + vw1 * bf2f(x1.u[e]) + vw2 * bf2f(x2.u[e]));
            hi.u[e] = f2bf(vw0 * bf2f(y0.u[e]) + vw1 * bf2f(y1.u[e]) + vw2 * bf2f(y2.u[e]));
        }
        int c0 = bkc >> 3;
        u16* dstB = &smem[2 * ASZ + buf * BSZ + brow * 64];
        *(uint4*)&dstB[((c0)     ^ (brow & 7)) * 8] = lo.v;
        *(uint4*)&dstB[((c0 + 1) ^ (brow & 7)) * 8] = hi.v;
    };
    auto stageA = [&](int buf, int k0) {
#pragma unroll
        for (int iss = 0; iss < 8; ++iss) {              // A: 256 rows, DMA
            int row = wv * 64 + iss * 8;
            const u16* g = A + (size_t)(row + rl) * KDIM + k0 + cg_;
            __builtin_amdgcn_global_load_lds(
                (const __attribute__((address_space(1))) unsigned int*)g,
                (__attribute__((address_space(3))) unsigned int*)(&smem[buf * ASZ + row * 64]),
                16, 0, 0);
        }
    };
    auto stageBdma = [&](int buf, int k0) {              // p1T DMA (K-contig)
#pragma unroll
        for (int iss = 0; iss < 2; ++iss) {
            int row = wv * 16 + iss * 8;
            const u16* g = p1T + (size_t)(cb0 + row + rl) * C1 + (k0 - C2) + cg_;
            __builtin_amdgcn_global_load_lds(
                (const __attribute__((address_space(1))) unsigned int*)g,
                (__attribute__((address_space(3))) unsigned int*)(&smem[2 * ASZ + buf * BSZ + row * 64]),
                16, 0, 0);
        }
    };

    f32x4 acc[8][NI] = {};

    // prologue: tile 0 (exposed once)
    loadB(0);
    stageA(0, 0);
    writeB(0);
    __syncthreads();

    for (int kt = 0; kt < KT; ++kt) {
        int nk = kt + 1;
        if (nk < KT) {                                    // issue next tile early
            stageA(nk & 1, nk * 64);
            if (nk * 64 < C2) loadB(nk * 64);
            else              stageBdma(nk & 1, nk * 64);
        }
        const u16* As = &smem[(kt & 1) * ASZ];
        const u16* Bs = &smem[2 * ASZ + (kt & 1) * BSZ];
#pragma unroll
        for (int ks = 0; ks < 2; ++ks) {
            int csw = ((ks * 4 + q) ^ (lm & 7)) * 8;      // un-swizzle chunk offset
            short8 av[8], bv[NI];
#pragma unroll
            for (int mi = 0; mi < 8; ++mi) {
                int mrow = (mi >> 2) * 128 + wm0 + (mi & 3) * 16;
                av[mi] = *(const short8*)&As[(mrow + lm) * 64 + csw];
            }
#pragma unroll
            for (int ni = 0; ni < NI; ++ni)
                bv[ni] = *(const short8*)&Bs[(wn0 + ni * 16 + lm) * 64 + csw];
#pragma unroll
            for (int mi = 0; mi < 8; ++mi)
#pragma unroll
                for (int ni = 0; ni < NI; ++ni)
                    acc[mi][ni] = __builtin_amdgcn_mfma_f32_16x16x32_bf16(
                        av[mi], bv[ni], acc[mi][ni], 0, 0, 0);
        }
        if (nk < KT) {
            if (nk * 64 < C2) writeB(nk & 1);             // vmcnt hidden by MFMA
            __syncthreads();                              // tile nk ready for all
        }
    }

    // ---- Epilogue (LDS overlay): Cs = 64 x 264 u16, reds = 512 floats ----
    u16*   Cs   = smem;                              // [colL*264 + m], m 0..255
    float* reds = (float*)&smem[COLT * 264];         // {256 sum, 256 sumsq}

    __syncthreads();                                  // all MFMA LDS reads done
    reds[t] = 0.f; reds[256 + t] = 0.f;
    __syncthreads();

#pragma unroll
    for (int mi = 0; mi < 8; ++mi) {
        int chL = (mi >> 2) * 128 + wm0 + (mi & 3) * 16 + q * 4;
        float bv4[4];
#pragma unroll
        for (int r = 0; r < 4; ++r) bv4[r] = bias[chL + r];
        float s[4]  = {0.f, 0.f, 0.f, 0.f};
        float s2[4] = {0.f, 0.f, 0.f, 0.f};
#pragma unroll
        for (int ni = 0; ni < NI; ++ni) {
            int colL = wn0 + ni * 16 + lm;
            union { u16 u[4]; uint2 d; } pk;
#pragma unroll
            for (int r = 0; r < 4; ++r) {
                float v = acc[mi][ni][r] + bv4[r];
                s[r]  += v;
                s2[r] += v * v;
                pk.u[r] = f2bf(v);
            }
            *(uint2*)&Cs[colL * 264 + chL] = pk.d;
        }
#pragma unroll
        for (int r = 0; r < 4; ++r) {
            float a = s[r], b2 = s2[r];
#pragma unroll
            for (int off = 1; off < 16; off <<= 1) {
                a  += __shfl_xor(a, off, 64);
                b2 += __shfl_xor(b2, off, 64);
            }
            if (lm == 0) {
                atomicAdd(&reds[chL + r], a);          // LDS atomic (on-CU)
                atomicAdd(&reds[256 + chL + r], b2);
            }
        }
    }
    __syncthreads();

    // coalesced C-store: 64 cols x 256 m; quarter-rows of 64 u16 = 8 x uint4
    {
        int c = t >> 2, h = t & 3;
        const u16* src = &Cs[c * 264 + h * 64];
        u16* dst = Ct + (size_t)(cb0 + c) * O0 + h * 64;
#pragma unroll
        for (int jj = 0; jj < 8; ++jj)
            *(uint4*)(dst + jj * 8) = *(const uint4*)(src + jj * 8);
    }
    // accumulate block stats into the super-record (depth 8 per address)
    int recIdx = blockIdx.x & (REC0 - 1);
    atomicAdd(&partials[(size_t)recIdx * 512 + t], reds[t]);
    atomicAdd(&partials[(size_t)recIdx * 512 + 256 + t], reds[256 + t]);
}

// ---------------------------------------------------------------------------
// K6: GEMM1 with T14 split; C-store goes DIRECTLY to out[b][c][n] as RAW
// (pre-BN1) f32 — no y1T round-trip. BN1+ReLU applied in-place by
// bn_relu_kernel after part1 is complete. Cs overlay is f32 transposed
// [chL*65 + colL] (conflict-free both sides).
__global__ __launch_bounds__(256) void gemm1_kernel(const u16* __restrict__ A,
                                                    const u16* __restrict__ Bt,
                                                    float* __restrict__ out,
                                                    const float* __restrict__ bias,
                                                    const float* __restrict__ redB,
                                                    const float* __restrict__ gB,
                                                    const float* __restrict__ beB,
                                                    float invN,
                                                    float* __restrict__ partials) {
    constexpr int KDIM = O0;             // 256
    constexpr int COLT = 64;
    constexpr int KT  = KDIM / 64;       // 4
    constexpr int NI  = COLT / 32;       // 2
    constexpr int ASZ = 128 * 64;
    constexpr int BSZ = COLT * 64;
    __shared__ u16 smem[2 * ASZ + 2 * BSZ];   // 49152 B; overlaid by CsT+reds
    __shared__ float sSc[KDIM];
    __shared__ float sSh[KDIM];

    int t   = threadIdx.x;
    int l   = t & 63;
    int wv  = t >> 6;
    int rl  = l >> 3;
    int cg_ = ((l & 7) ^ rl) * 8;
    int cb0 = blockIdx.x * COLT;
    int lm  = l & 15;
    int q   = l >> 4;
    int wm0 = (wv & 1) * 64;
    int wn0 = (wv >> 1) * (COLT / 2);
    int brow = t >> 2;                   // 0..63
    int bkc  = (t & 3) * 16;

    {   // fold BN0 super-record stats into scale/shift (t = channel 0..255)
        float s = 0.f, s2 = 0.f;
#pragma unroll 8
        for (int i = 0; i < REC0; ++i) {
            s  += redB[i * 512 + t];
            s2 += redB[i * 512 + 256 + t];
        }
        float mean = s * invN;
        float var  = fmaxf(s2 * invN - mean * mean, 0.f);
        float inv  = rsqrtf(var + BN_EPS);
        float sc   = gB[t] * inv;
        sSc[t] = sc;
        sSh[t] = beB[t] - mean * sc;
        __syncthreads();
    }

    uint4 bl0, bl1;                      // in-flight y0T regs
    auto loadB = [&](int k0) {
        const u16* gp = Bt + (size_t)(cb0 + brow) * KDIM + k0 + bkc;
        bl0 = *(const uint4*)gp;
        bl1 = *(const uint4*)(gp + 8);
    };
    auto writeB = [&](int buf, int k0) { // relu(f*sc+sh) + swizzled LDS store
        union U { uint4 v; u16 u[8]; } lo, hi;
        lo.v = bl0; hi.v = bl1;
#pragma unroll
        for (int e = 0; e < 8; ++e) {
            float f0 = bf2f(lo.u[e]);
            lo.u[e] = f2bf(fmaxf(f0 * sSc[k0 + bkc + e] + sSh[k0 + bkc + e], 0.f));
            float f1 = bf2f(hi.u[e]);
            hi.u[e] = f2bf(fmaxf(f1 * sSc[k0 + bkc + 8 + e] + sSh[k0 + bkc + 8 + e], 0.f));
        }
        int c0 = bkc >> 3;
        u16* dstB = &smem[2 * ASZ + buf * BSZ + brow * 64];
        *(uint4*)&dstB[((c0)     ^ (brow & 7)) * 8] = lo.v;
        *(uint4*)&dstB[((c0 + 1) ^ (brow & 7)) * 8] = hi.v;
    };
    auto stageA = [&](int buf, int k0) {
#pragma unroll
        for (int iss = 0; iss < 4; ++iss) {              // A: 128 rows, DMA
            int row = wv * 32 + iss * 8;
            const u16* g = A + (size_t)(row + rl) * KDIM + k0 + cg_;
            __builtin_amdgcn_global_load_lds(
                (const __attribute__((address_space(1))) unsigned int*)g,
                (__attribute__((address_space(3))) unsigned int*)(&smem[buf * ASZ + row * 64]),
                16, 0, 0);
        }
    };

    f32x4 acc[4][NI] = {};

    // prologue: tile 0 (exposed once)
    loadB(0);
    stageA(0, 0);
    writeB(0, 0);
    __syncthreads();

    for (int kt = 0; kt < KT; ++kt) {
        int nk = kt + 1;
        if (nk < KT) {
            stageA(nk & 1, nk * 64);
            loadB(nk * 64);
        }
        const u16* As = &smem[(kt & 1) * ASZ];
        const u16* Bs = &smem[2 * ASZ + (kt & 1) * BSZ];
#pragma unroll
        for (int ks = 0; ks < 2; ++ks) {
            int csw = ((ks * 4 + q) ^ (lm & 7)) * 8;
            short8 av[4], bv[NI];
#pragma unroll
            for (int mi = 0; mi < 4; ++mi)
                av[mi] = *(const short8*)&As[(wm0 + mi * 16 + lm) * 64 + csw];
#pragma unroll
            for (int ni = 0; ni < NI; ++ni)
                bv[ni] = *(const short8*)&Bs[(wn0 + ni * 16 + lm) * 64 + csw];
#pragma unroll
            for (int mi = 0; mi < 4; ++mi)
#pragma unroll
                for (int ni = 0; ni < NI; ++ni)
                    acc[mi][ni] = __builtin_amdgcn_mfma_f32_16x16x32_bf16(
                        av[mi], bv[ni], acc[mi][ni], 0, 0, 0);
        }
        if (nk < KT) {
            writeB(nk & 1, nk * 64);                      // vmcnt hidden by MFMA
            __syncthreads();
        }
    }

    // ---- Epilogue (LDS overlay): CsT = f32 [chL*65 + colL], reds after ----
    float* CsT  = (float*)smem;                      // 128 x 65 f32 = 33280 B
    float* reds = CsT + 128 * 65;                    // 256 floats

    __syncthreads();                                  // all MFMA LDS reads done
    if (t < 256) reds[t] = 0.f;
    __syncthreads();

#pragma unroll
    for (int mi = 0; mi < 4; ++mi) {
        int chL = wm0 + mi * 16 + q * 4;
        float bv4[4];
#pragma unroll
        for (int r = 0; r < 4; ++r) bv4[r] = bias[chL + r];
        float s[4]  = {0.f, 0.f, 0.f, 0.f};
        float s2[4] = {0.f, 0.f, 0.f, 0.f};
#pragma unroll
        for (int ni = 0; ni < NI; ++ni) {
            int colL = wn0 + ni * 16 + lm;
#pragma unroll
            for (int r = 0; r < 4; ++r) {
                float v = acc[mi][ni][r] + bv4[r];
                s[r]  += v;
                s2[r] += v * v;
                CsT[(chL + r) * 65 + colL] = v;      // lanes -> consecutive colL
            }
        }
#pragma unroll
        for (int r = 0; r < 4; ++r) {
            float a = s[r], b2 = s2[r];
#pragma unroll
            for (int off = 1; off < 16; off <<= 1) {
                a  += __shfl_xor(a, off, 64);
                b2 += __shfl_xor(b2, off, 64);
            }
            if (lm == 0) {
                atomicAdd(&reds[chL + r], a);
                atomicAdd(&reds[128 + chL + r], b2);
            }
        }
    }
    __syncthreads();

    // direct transposed f32 store: out[bb][c][n0+nl] (raw, pre-BN1)
    {
        int bb = cb0 >> 13;              // COLT divides NN: no batch straddle
        int n0 = cb0 & (NN - 1);
        float* obase = out + (size_t)bb * O1 * NN + n0;
        int nl = t & 63;
#pragma unroll
        for (int it = 0; it < 32; ++it) {
            int c = it * 4 + (t >> 6);   // 0..127
            obase[(size_t)c * NN + nl] = CsT[c * 65 + nl];
        }
    }
    int recIdx = blockIdx.x & (REC1 - 1);
    atomicAdd(&partials[(size_t)recIdx * 256 + t], reds[t]);
}

// ---------------------------------------------------------------------------
// K8: in-place BN1+ReLU over out[b][c][:]. One block per (b,c) pair; each
// thread folds part1 (L2-resident, 32 KB) redundantly, then streams the row.
__global__ __launch_bounds__(256) void bn_relu_kernel(float* __restrict__ out,
                                                      const float* __restrict__ part1,
                                                      const float* __restrict__ g1,
                                                      const float* __restrict__ be1,
                                                      float invN) {
    int bid = blockIdx.x;                // 512 = 4 batches x 128 channels
    int c  = bid & 127;
    int bb = bid >> 7;

    float s = 0.f, s2 = 0.f;
#pragma unroll 8
    for (int i = 0; i < REC1; ++i) {
        s  += part1[i * 256 + c];
        s2 += part1[i * 256 + 128 + c];
    }
    float mean = s * invN;
    float var  = fmaxf(s2 * invN - mean * mean, 0.f);
    float inv  = rsqrtf(var + BN_EPS);
    float sc   = g1[c] * inv;
    float sh   = be1[c] - mean * sc;

    float4* p = (float4*)(out + (size_t)bb * O1 * NN + (size_t)c * NN);
    int t = threadIdx.x;
#pragma unroll
    for (int j = 0; j < NN / 4 / 256; ++j) {       // 8 float4 per thread
        float4 v = p[j * 256 + t];
        v.x = fmaxf(v.x * sc + sh, 0.f);
        v.y = fmaxf(v.y * sc + sh, 0.f);
        v.z = fmaxf(v.z * sc + sh, 0.f);
        v.w = fmaxf(v.w * sc + sh, 0.f);
        p[j * 256 + t] = v;
    }
}

// ---------------------------------------------------------------------------
extern "C" void kernel_launch(void* const* d_in, const int* in_sizes, int n_in,
                              void* d_out, int out_size, void* d_ws, size_t ws_size,
                              hipStream_t stream) {
    (void)in_sizes; (void)n_in; (void)out_size; (void)ws_size;

    const float* xyz1    = (const float*)d_in[0];
    const float* xyz2    = (const float*)d_in[1];
    const float* norm1   = (const float*)d_in[2];
    const float* norm2   = (const float*)d_in[3];
    const float* points1 = (const float*)d_in[4];
    const float* points2 = (const float*)d_in[5];
    const float* W0f     = (const float*)d_in[6];
    const float* b0      = (const float*)d_in[7];
    const float* g0      = (const float*)d_in[8];
    const float* be0     = (const float*)d_in[9];
    const float* W1f     = (const float*)d_in[10];
    const float* b1      = (const float*)d_in[11];
    const float* g1      = (const float*)d_in[12];
    const float* be1     = (const float*)d_in[13];
    float* out = (float*)d_out;

    // workspace carve-up (all 256B-aligned)
    char* w8 = (char*)d_ws;
    size_t off = 0;
    auto carve = [&](size_t bytes) { void* p = w8 + off; off += (bytes + 255) & ~(size_t)255; return p; };
    int*   idxW   = (int*)  carve((size_t)NCOL * 3 * sizeof(int));
    float* wW     = (float*)carve((size_t)NCOL * 3 * sizeof(float));
    u16*   p2T    = (u16*)  carve((size_t)BB * MM * C2 * 2);
    u16*   p1T    = (u16*)  carve((size_t)BB * NN * C1 * 2);
    u16*   W0b    = (u16*)  carve((size_t)O0 * CH0 * 2);
    u16*   W1b    = (u16*)  carve((size_t)O1 * O0 * 2);
    u16*   y0T    = (u16*)  carve((size_t)NCOL * O0 * 2);
    float* part0  = (float*)carve((size_t)REC0 * 512 * sizeof(float));  // 128 KB
    float* part1  = (float*)carve((size_t)REC1 * 256 * sizeof(float));  // 32 KB

    const float invN = 1.0f / (float)NCOL;

    // 1024 3-NN blocks + 6656 prep blocks + 160 zero blocks
    fused_pre_kernel<<<7840, 256, 0, stream>>>(
        xyz1, xyz2, norm1, norm2, idxW, wW,
        points2, p2T, points1, p1T, W0f, W0b, W1f, W1b, part0, part1);

    // GEMM0 (merged y-halves, T14 async-STAGE split)
    gemm0_kernel<<<NCOL / 64, 256, 0, stream>>>(
        W0b, p2T, p1T, idxW, wW, y0T, b0, part0);

    // GEMM1 (T14 split): raw f32 output direct to out[b][c][n]; stats to part1
    gemm1_kernel<<<NCOL / 64, 256, 0, stream>>>(
        W1b, y0T, out, b1, part0, g0, be0, invN, part1);

    // in-place BN1+ReLU (replaces the y1T round-trip finalize)
    bn_relu_kernel<<<BB * O1, 256, 0, stream>>>(out, part1, g1, be1, invN);
}

// Round 11
// 180.710 us; speedup vs baseline: 1.0475x; 1.0024x over previous
//
#include <hip/hip_runtime.h>
#include <hip/hip_bf16.h>
#include <cstdint>
#include <cstddef>

// Problem constants (B,N,M,C2,C1) = (4, 8192, 2048, 256, 128)
static constexpr int BB   = 4;
static constexpr int NN   = 8192;
static constexpr int MM   = 2048;
static constexpr int C1   = 128;
static constexpr int C2   = 256;
static constexpr int CH0  = C2 + C1;   // 384  (K of GEMM0)
static constexpr int O0   = 256;       // out channels layer 0
static constexpr int O1   = 128;       // out channels layer 1
static constexpr int NCOL = BB * NN;   // 32768 columns
static constexpr float BN_EPS = 1e-5f;

// BN-stats super-records (atomicAdd targets; depth <= 16 per address)
// part0: REC0 records of 512 floats {256 sums, 256 sumsqs}  (gemm0, M=256/block)
// part1: REC1 records of 256 floats {128 sums, 128 sumsqs}  (gemm1)
static constexpr int REC0 = 64;
static constexpr int REC1 = 32;

// 3-NN geometry: 16 queries/block, 16 lanes/query -> 2048 blocks (8/CU,
// 32 waves/CU = max occupancy) with 128 candidates/lane.
static constexpr int NB3  = NCOL / 16;           // 2048 blocks
static constexpr int PREP = 6656;
static constexpr int ZB   = 160;

using u16 = unsigned short;
typedef __attribute__((ext_vector_type(8))) short short8;
typedef __attribute__((ext_vector_type(4))) float f32x4;

static __device__ __forceinline__ float bf2f(u16 u) {
    union { unsigned int i; float f; } v; v.i = ((unsigned int)u) << 16; return v.f;
}
static __device__ __forceinline__ u16 f2bf(float f) {
    union { float f; unsigned int i; } v; v.f = f;
    unsigned int r = (v.i + 0x7fffu + ((v.i >> 16) & 1u)) >> 16;
    return (u16)r;
}

// ---------------------------------------------------------------------------
// K1 (fused pre-stage): blocks [0,NB3) = 3-NN (16 lanes/query, qq-free scan:
// d' = fmaf(qx,Px,fmaf(qy,Py,fmaf(qz,Pz,Pw))) — ordering per query invariant
// to the +qq constant, added back post-merge); [NB3,NB3+PREP) = transposes +
// weight casts; last ZB = zero super-records.
__global__ __launch_bounds__(256) void fused_pre_kernel(
        const float* __restrict__ xyz1,  const float* __restrict__ xyz2,
        const float* __restrict__ norm1, const float* __restrict__ norm2,
        int* __restrict__ idxOut, float* __restrict__ wOut,
        const float* __restrict__ points2, u16* __restrict__ p2T,
        const float* __restrict__ points1, u16* __restrict__ p1T,
        const float* __restrict__ W0f, u16* __restrict__ W0b,
        const float* __restrict__ W1f, u16* __restrict__ W1b,
        float* __restrict__ part0, float* __restrict__ part1) {
#pragma clang fp contract(off)
    __shared__ union { float4 pts[1024]; float tile[32][33]; } sm;
    int id = blockIdx.x;
    int t  = threadIdx.x;

    if (id >= NB3 + PREP) {                 // ---- zero super-records ----
        int flat = (id - (NB3 + PREP)) * 256 + t;   // 160*256 = 40960 floats
        if (flat < REC0 * 512) part0[flat] = 0.f;
        else part1[flat - REC0 * 512] = 0.f;
        return;
    }
    if (id >= NB3) {                        // ---- prep: transpose / cast ----
        int pid = id - NB3;
        if (pid < 6144) {
            const float* in; u16* out; int R, C, b, c0, r0;
            if (pid < 2048) {
                in = points2; out = p2T; R = C2; C = MM;
                b = pid >> 9; int rem = pid & 511;
                c0 = (rem & 63) * 32; r0 = (rem >> 6) * 32;
            } else {
                int id2 = pid - 2048;
                in = points1; out = p1T; R = C1; C = NN;
                b = id2 >> 10; int rem = id2 & 1023;
                c0 = (rem & 255) * 32; r0 = (rem >> 8) * 32;
            }
            int tx = t & 31, ty = t >> 5;
            const float* pin = in + (size_t)b * R * C;
            u16* pout = out + (size_t)b * R * C;
#pragma unroll
            for (int j = 0; j < 4; ++j) {
                int r = ty + j * 8;
                sm.tile[r][tx] = pin[(size_t)(r0 + r) * C + (c0 + tx)];
            }
            __syncthreads();
#pragma unroll
            for (int j = 0; j < 4; ++j) {
                int c = ty + j * 8;
                pout[(size_t)(c0 + c) * R + (r0 + tx)] = f2bf(sm.tile[tx][c]);
            }
        } else {
            int i = (pid - 6144) * 256 + t;
            if (i < O0 * CH0) W0b[i] = f2bf(W0f[i]);
            else {
                int i2 = i - O0 * CH0;
                if (i2 < O1 * O0) W1b[i2] = f2bf(W1f[i2]);
            }
        }
        return;
    }

    // ---- 3-NN: 16 queries/block, 16 candidate-lanes/query ----
    int b    = id >> 9;                  // 512 blocks of 16 queries per batch
    int nblk = id & 511;
    int j    = t & 15;                   // candidate partition lane (0..15)
    int g    = t >> 4;                   // query group 0..15

    int n = nblk * 16 + g;
    const float* x1 = xyz1 + (size_t)b * 3 * NN;
    float qx = x1[n], qy = x1[NN + n], qz = x1[2 * NN + n];
    float qq = __builtin_fmaf(qx, qx, __builtin_fmaf(qy, qy, qz * qz));

    const float* x2 = xyz2 + (size_t)b * 3 * MM;

    float d0 = 3.4e38f, d1 = 3.4e38f, d2v = 3.4e38f;
    int   i0 = 0, i1 = 0, i2 = 0;

    for (int chunk = 0; chunk < MM / 1024; ++chunk) {
        __syncthreads();
        for (int i = t; i < 1024; i += 256) {
            int m = chunk * 1024 + i;
            float px = x2[m];
            float py = x2[MM + m];
            float pz = x2[2 * MM + m];
            float pp = __builtin_fmaf(px, px, __builtin_fmaf(py, py, pz * pz));
            // store (-2px, -2py, -2pz, pp): qq-free distance = 3 fma
            sm.pts[i] = make_float4(-2.0f * px, -2.0f * py, -2.0f * pz, pp);
        }
        __syncthreads();

#pragma unroll 8
        for (int s = 0; s < 1024 / 16; ++s) {
            int ml = s * 16 + j;         // ascending per lane -> stable ties
            float4 P = sm.pts[ml];
            float d  = __builtin_fmaf(qx, P.x,
                        __builtin_fmaf(qy, P.y,
                         __builtin_fmaf(qz, P.z, P.w)));   // d' = d - qq
            if (d < d2v) {
                int m = chunk * 1024 + ml;
                if (d < d1) {
                    if (d < d0) { d2v = d1; i2 = i1; d1 = d0; i1 = i0; d0 = d; i0 = m; }
                    else        { d2v = d1; i2 = i1; d1 = d;  i1 = m; }
                } else          { d2v = d;  i2 = m; }
            }
        }
    }

    // merge sorted triples across the 16 lanes (lexicographic tie-break)
#pragma unroll
    for (int k = 1; k <= 8; k <<= 1) {
        float e0 = __shfl_xor(d0, k, 64), e1 = __shfl_xor(d1, k, 64), e2 = __shfl_xor(d2v, k, 64);
        int   f0 = __shfl_xor(i0, k, 64), f1 = __shfl_xor(i1, k, 64), f2 = __shfl_xor(i2, k, 64);
        float ed[3] = {e0, e1, e2}; int ef[3] = {f0, f1, f2};
#pragma unroll
        for (int e = 0; e < 3; ++e) {
            float dd = ed[e]; int ff = ef[e];
            bool b2 = (dd < d2v) || (dd == d2v && ff < i2);
            if (b2) {
                bool b1 = (dd < d1) || (dd == d1 && ff < i1);
                if (b1) {
                    d2v = d1; i2 = i1;
                    bool b0 = (dd < d0) || (dd == d0 && ff < i0);
                    if (b0) { d1 = d0; i1 = i0; d0 = dd; i0 = ff; }
                    else    { d1 = dd; i1 = ff; }
                } else { d2v = dd; i2 = ff; }
            }
        }
    }

    if (j == 0) {
        // add qq back before sqrt (scan used d' = d - qq)
        float s0 = sqrtf(fmaxf(d0 + qq, 1e-20f));
        float s1 = sqrtf(fmaxf(d1 + qq, 1e-20f));
        float s2 = sqrtf(fmaxf(d2v + qq, 1e-20f));
        float r0 = 1.0f / fmaxf(s0, 1e-10f);
        float r1 = 1.0f / fmaxf(s1, 1e-10f);
        float r2 = 1.0f / fmaxf(s2, 1e-10f);
        float rs = (r0 + r1) + r2;
        float w0 = r0 / rs, w1 = r1 / rs, w2 = r2 / rs;

        const float* nm1 = norm1 + (size_t)b * 3 * NN;
        const float* nm2 = norm2 + (size_t)b * 3 * MM;
        float ax = nm1[n], ay = nm1[NN + n], az = nm1[2 * NN + n];
        float nd[3]; int ii[3] = {i0, i1, i2};
#pragma unroll
        for (int k = 0; k < 3; ++k) {
            int ik = ii[k];
            float dx = ax - nm2[ik];
            float dy = ay - nm2[MM + ik];
            float dz = az - nm2[2 * MM + ik];
            nd[k] = sqrtf((dx * dx + dy * dy) + dz * dz);
        }
        float m0 = 1.0f / fmaxf(nd[0], 1e-10f);
        float m1 = 1.0f / fmaxf(nd[1], 1e-10f);
        float m2 = 1.0f / fmaxf(nd[2], 1e-10f);
        float ms = (m0 + m1) + m2;

        int col = b * NN + n;
        idxOut[col * 3 + 0] = i0;
        idxOut[col * 3 + 1] = i1;
        idxOut[col * 3 + 2] = i2;
        wOut[col * 3 + 0] = w0 * (m0 / ms);
        wOut[col * 3 + 1] = w1 * (m1 / ms);
        wOut[col * 3 + 2] = w2 * (m2 / ms);
    }
}

// ---------------------------------------------------------------------------
// K4: GEMM0, merged y-halves, T14 async-STAGE split: B-gather loads issued
// BEFORE the MFMA phase (latency hides under compute), interp+ds_write AFTER.
// A via global_load_lds (drained by end-of-iter barrier -> also hidden).
// 256 rows x 64 cols, BK=64, 6 K-steps, 80 KB LDS -> 2 blocks/CU.
__global__ __launch_bounds__(256, 2) void gemm0_kernel(
        const u16* __restrict__ A,       // W0b (256 x 384)
        const u16* __restrict__ Bt,      // p2T
        const u16* __restrict__ p1T,
        const int* __restrict__ idx,
        const float* __restrict__ w,
        u16* __restrict__ Ct,            // y0T (col-major, LD = O0)
        const float* __restrict__ bias,  // b0
        float* __restrict__ partials) {  // part0 [REC0][512]
    constexpr int KDIM = CH0;            // 384
    constexpr int COLT = 64;
    constexpr int KT  = KDIM / 64;       // 6
    constexpr int NI  = COLT / 32;       // 2
    constexpr int ASZ = 256 * 64;        // u16 per A buffer (32 KB)
    constexpr int BSZ = COLT * 64;       // u16 per B buffer (8 KB)
    __shared__ u16 smem[2 * ASZ + 2 * BSZ];   // 81920 B

    int t   = threadIdx.x;
    int l   = t & 63;
    int wv  = t >> 6;
    int rl  = l >> 3;                    // staging row-in-group 0..7
    int cg_ = ((l & 7) ^ rl) * 8;        // swizzled global chunk (elements)
    int cb0 = blockIdx.x * COLT;
    int lm  = l & 15;
    int q   = l >> 4;
    int wm0 = (wv & 1) * 64;
    int wn0 = (wv >> 1) * (COLT / 2);

    // per-thread column interpolation params
    int colg = cb0 + (t >> 2);
    int vi0 = idx[colg * 3 + 0], vi1 = idx[colg * 3 + 1], vi2 = idx[colg * 3 + 2];
    float vw0 = w[colg * 3 + 0], vw1 = w[colg * 3 + 1], vw2 = w[colg * 3 + 2];
    const u16* p2base = Bt + (size_t)(cb0 >> 13) * MM * C2;
    int brow = t >> 2;                   // 0..63
    int bkc  = (t & 3) * 16;

    uint4 bl[6];                         // in-flight gather regs (24 VGPR)
    auto loadB = [&](int k0) {           // ISSUE ONLY — no wait here
        const u16* bp  = p2base + k0 + bkc;
        const u16* r0p = bp + (size_t)vi0 * C2;
        const u16* r1p = bp + (size_t)vi1 * C2;
        const u16* r2p = bp + (size_t)vi2 * C2;
        bl[0] = *(const uint4*)r0p; bl[1] = *(const uint4*)(r0p + 8);
        bl[2] = *(const uint4*)r1p; bl[3] = *(const uint4*)(r1p + 8);
        bl[4] = *(const uint4*)r2p; bl[5] = *(const uint4*)(r2p + 8);
    };
    auto writeB = [&](int buf) {         // interp + swizzled LDS store (waits vmcnt)
        union U { uint4 v; u16 u[8]; } x0, y0, x1, y1, x2, y2, lo, hi;
        x0.v = bl[0]; y0.v = bl[1];
        x1.v = bl[2]; y1.v = bl[3];
        x2.v = bl[4]; y2.v = bl[5];
#pragma unroll
        for (int e = 0; e < 8; ++e) {
            lo.u[e] = f2bf(vw0 * bf2f(x0.u[e]) + vw1 * bf2f(x1.u[e]) + vw2 * bf2f(x2.u[e]));
            hi.u[e] = f2bf(vw0 * bf2f(y0.u[e]) + vw1 * bf2f(y1.u[e]) + vw2 * bf2f(y2.u[e]));
        }
        int c0 = bkc >> 3;
        u16* dstB = &smem[2 * ASZ + buf * BSZ + brow * 64];
        *(uint4*)&dstB[((c0)     ^ (brow & 7)) * 8] = lo.v;
        *(uint4*)&dstB[((c0 + 1) ^ (brow & 7)) * 8] = hi.v;
    };
    auto stageA = [&](int buf, int k0) {
#pragma unroll
        for (int iss = 0; iss < 8; ++iss) {              // A: 256 rows, DMA
            int row = wv * 64 + iss * 8;
            const u16* g = A + (size_t)(row + rl) * KDIM + k0 + cg_;
            __builtin_amdgcn_global_load_lds(
                (const __attribute__((address_space(1))) unsigned int*)g,
                (__attribute__((address_space(3))) unsigned int*)(&smem[buf * ASZ + row * 64]),
                16, 0, 0);
        }
    };
    auto stageBdma = [&](int buf, int k0) {              // p1T DMA (K-contig)
#pragma unroll
        for (int iss = 0; iss < 2; ++iss) {
            int row = wv * 16 + iss * 8;
            const u16* g = p1T + (size_t)(cb0 + row + rl) * C1 + (k0 - C2) + cg_;
            __builtin_amdgcn_global_load_lds(
                (const __attribute__((address_space(1))) unsigned int*)g,
                (__attribute__((address_space(3))) unsigned int*)(&smem[2 * ASZ + buf * BSZ + row * 64]),
                16, 0, 0);
        }
    };

    f32x4 acc[8][NI] = {};

    // prologue: tile 0 (exposed once)
    loadB(0);
    stageA(0, 0);
    writeB(0);
    __syncthreads();

    for (int kt = 0; kt < KT; ++kt) {
        int nk = kt + 1;
        if (nk < KT) {                                    // issue next tile early
            stageA(nk & 1, nk * 64);
            if (nk * 64 < C2) loadB(nk * 64);
            else              stageBdma(nk & 1, nk * 64);
        }
        const u16* As = &smem[(kt & 1) * ASZ];
        const u16* Bs = &smem[2 * ASZ + (kt & 1) * BSZ];
#pragma unroll
        for (int ks = 0; ks < 2; ++ks) {
            int csw = ((ks * 4 + q) ^ (lm & 7)) * 8;      // un-swizzle chunk offset
            short8 av[8], bv[NI];
#pragma unroll
            for (int mi = 0; mi < 8; ++mi) {
                int mrow = (mi >> 2) * 128 + wm0 + (mi & 3) * 16;
                av[mi] = *(const short8*)&As[(mrow + lm) * 64 + csw];
            }
#pragma unroll
            for (int ni = 0; ni < NI; ++ni)
                bv[ni] = *(const short8*)&Bs[(wn0 + ni * 16 + lm) * 64 + csw];
#pragma unroll
            for (int mi = 0; mi < 8; ++mi)
#pragma unroll
                for (int ni = 0; ni < NI; ++ni)
                    acc[mi][ni] = __builtin_amdgcn_mfma_f32_16x16x32_bf16(
                        av[mi], bv[ni], acc[mi][ni], 0, 0, 0);
        }
        if (nk < KT) {
            if (nk * 64 < C2) writeB(nk & 1);             // vmcnt hidden by MFMA
            __syncthreads();                              // tile nk ready for all
        }
    }

    // ---- Epilogue (LDS overlay): Cs = 64 x 264 u16, reds = 512 floats ----
    u16*   Cs   = smem;                              // [colL*264 + m], m 0..255
    float* reds = (float*)&smem[COLT * 264];         // {256 sum, 256 sumsq}

    __syncthreads();                                  // all MFMA LDS reads done
    reds[t] = 0.f; reds[256 + t] = 0.f;
    __syncthreads();

#pragma unroll
    for (int mi = 0; mi < 8; ++mi) {
        int chL = (mi >> 2) * 128 + wm0 + (mi & 3) * 16 + q * 4;
        float bv4[4];
#pragma unroll
        for (int r = 0; r < 4; ++r) bv4[r] = bias[chL + r];
        float s[4]  = {0.f, 0.f, 0.f, 0.f};
        float s2[4] = {0.f, 0.f, 0.f, 0.f};
#pragma unroll
        for (int ni = 0; ni < NI; ++ni) {
            int colL = wn0 + ni * 16 + lm;
            union { u16 u[4]; uint2 d; } pk;
#pragma unroll
            for (int r = 0; r < 4; ++r) {
                float v = acc[mi][ni][r] + bv4[r];
                s[r]  += v;
                s2[r] += v * v;
                pk.u[r] = f2bf(v);
            }
            *(uint2*)&Cs[colL * 264 + chL] = pk.d;
        }
#pragma unroll
        for (int r = 0; r < 4; ++r) {
            float a = s[r], b2 = s2[r];
#pragma unroll
            for (int off = 1; off < 16; off <<= 1) {
                a  += __shfl_xor(a, off, 64);
                b2 += __shfl_xor(b2, off, 64);
            }
            if (lm == 0) {
                atomicAdd(&reds[chL + r], a);          // LDS atomic (on-CU)
                atomicAdd(&reds[256 + chL + r], b2);
            }
        }
    }
    __syncthreads();

    // coalesced C-store: 64 cols x 256 m; quarter-rows of 64 u16 = 8 x uint4
    {
        int c = t >> 2, h = t & 3;
        const u16* src = &Cs[c * 264 + h * 64];
        u16* dst = Ct + (size_t)(cb0 + c) * O0 + h * 64;
#pragma unroll
        for (int jj = 0; jj < 8; ++jj)
            *(uint4*)(dst + jj * 8) = *(const uint4*)(src + jj * 8);
    }
    // accumulate block stats into the super-record (depth 8 per address)
    int recIdx = blockIdx.x & (REC0 - 1);
    atomicAdd(&partials[(size_t)recIdx * 512 + t], reds[t]);
    atomicAdd(&partials[(size_t)recIdx * 512 + 256 + t], reds[256 + t]);
}

// ---------------------------------------------------------------------------
// K6: GEMM1 with T14 split; C-store goes DIRECTLY to out[b][c][n] as RAW
// (pre-BN1) f32 — no y1T round-trip. BN1+ReLU applied in-place by
// bn_relu_kernel after part1 is complete.
__global__ __launch_bounds__(256) void gemm1_kernel(const u16* __restrict__ A,
                                                    const u16* __restrict__ Bt,
                                                    float* __restrict__ out,
                                                    const float* __restrict__ bias,
                                                    const float* __restrict__ redB,
                                                    const float* __restrict__ gB,
                                                    const float* __restrict__ beB,
                                                    float invN,
                                                    float* __restrict__ partials) {
    constexpr int KDIM = O0;             // 256
    constexpr int COLT = 64;
    constexpr int KT  = KDIM / 64;       // 4
    constexpr int NI  = COLT / 32;       // 2
    constexpr int ASZ = 128 * 64;
    constexpr int BSZ = COLT * 64;
    __shared__ u16 smem[2 * ASZ + 2 * BSZ];   // 49152 B; overlaid by CsT+reds
    __shared__ float sSc[KDIM];
    __shared__ float sSh[KDIM];

    int t   = threadIdx.x;
    int l   = t & 63;
    int wv  = t >> 6;
    int rl  = l >> 3;
    int cg_ = ((l & 7) ^ rl) * 8;
    int cb0 = blockIdx.x * COLT;
    int lm  = l & 15;
    int q   = l >> 4;
    int wm0 = (wv & 1) * 64;
    int wn0 = (wv >> 1) * (COLT / 2);
    int brow = t >> 2;                   // 0..63
    int bkc  = (t & 3) * 16;

    {   // fold BN0 super-record stats into scale/shift (t = channel 0..255)
        float s = 0.f, s2 = 0.f;
#pragma unroll 8
        for (int i = 0; i < REC0; ++i) {
            s  += redB[i * 512 + t];
            s2 += redB[i * 512 + 256 + t];
        }
        float mean = s * invN;
        float var  = fmaxf(s2 * invN - mean * mean, 0.f);
        float inv  = rsqrtf(var + BN_EPS);
        float sc   = gB[t] * inv;
        sSc[t] = sc;
        sSh[t] = beB[t] - mean * sc;
        __syncthreads();
    }

    uint4 bl0, bl1;                      // in-flight y0T regs
    auto loadB = [&](int k0) {
        const u16* gp = Bt + (size_t)(cb0 + brow) * KDIM + k0 + bkc;
        bl0 = *(const uint4*)gp;
        bl1 = *(const uint4*)(gp + 8);
    };
    auto writeB = [&](int buf, int k0) { // relu(f*sc+sh) + swizzled LDS store
        union U { uint4 v; u16 u[8]; } lo, hi;
        lo.v = bl0; hi.v = bl1;
#pragma unroll
        for (int e = 0; e < 8; ++e) {
            float f0 = bf2f(lo.u[e]);
            lo.u[e] = f2bf(fmaxf(f0 * sSc[k0 + bkc + e] + sSh[k0 + bkc + e], 0.f));
            float f1 = bf2f(hi.u[e]);
            hi.u[e] = f2bf(fmaxf(f1 * sSc[k0 + bkc + 8 + e] + sSh[k0 + bkc + 8 + e], 0.f));
        }
        int c0 = bkc >> 3;
        u16* dstB = &smem[2 * ASZ + buf * BSZ + brow * 64];
        *(uint4*)&dstB[((c0)     ^ (brow & 7)) * 8] = lo.v;
        *(uint4*)&dstB[((c0 + 1) ^ (brow & 7)) * 8] = hi.v;
    };
    auto stageA = [&](int buf, int k0) {
#pragma unroll
        for (int iss = 0; iss < 4; ++iss) {              // A: 128 rows, DMA
            int row = wv * 32 + iss * 8;
            const u16* g = A + (size_t)(row + rl) * KDIM + k0 + cg_;
            __builtin_amdgcn_global_load_lds(
                (const __attribute__((address_space(1))) unsigned int*)g,
                (__attribute__((address_space(3))) unsigned int*)(&smem[buf * ASZ + row * 64]),
                16, 0, 0);
        }
    };

    f32x4 acc[4][NI] = {};

    // prologue: tile 0 (exposed once)
    loadB(0);
    stageA(0, 0);
    writeB(0, 0);
    __syncthreads();

    for (int kt = 0; kt < KT; ++kt) {
        int nk = kt + 1;
        if (nk < KT) {
            stageA(nk & 1, nk * 64);
            loadB(nk * 64);
        }
        const u16* As = &smem[(kt & 1) * ASZ];
        const u16* Bs = &smem[2 * ASZ + (kt & 1) * BSZ];
#pragma unroll
        for (int ks = 0; ks < 2; ++ks) {
            int csw = ((ks * 4 + q) ^ (lm & 7)) * 8;
            short8 av[4], bv[NI];
#pragma unroll
            for (int mi = 0; mi < 4; ++mi)
                av[mi] = *(const short8*)&As[(wm0 + mi * 16 + lm) * 64 + csw];
#pragma unroll
            for (int ni = 0; ni < NI; ++ni)
                bv[ni] = *(const short8*)&Bs[(wn0 + ni * 16 + lm) * 64 + csw];
#pragma unroll
            for (int mi = 0; mi < 4; ++mi)
#pragma unroll
                for (int ni = 0; ni < NI; ++ni)
                    acc[mi][ni] = __builtin_amdgcn_mfma_f32_16x16x32_bf16(
                        av[mi], bv[ni], acc[mi][ni], 0, 0, 0);
        }
        if (nk < KT) {
            writeB(nk & 1, nk * 64);                      // vmcnt hidden by MFMA
            __syncthreads();
        }
    }

    // ---- Epilogue (LDS overlay): CsT = f32 [chL*65 + colL], reds after ----
    float* CsT  = (float*)smem;                      // 128 x 65 f32 = 33280 B
    float* reds = CsT + 128 * 65;                    // 256 floats

    __syncthreads();                                  // all MFMA LDS reads done
    if (t < 256) reds[t] = 0.f;
    __syncthreads();

#pragma unroll
    for (int mi = 0; mi < 4; ++mi) {
        int chL = wm0 + mi * 16 + q * 4;
        float bv4[4];
#pragma unroll
        for (int r = 0; r < 4; ++r) bv4[r] = bias[chL + r];
        float s[4]  = {0.f, 0.f, 0.f, 0.f};
        float s2[4] = {0.f, 0.f, 0.f, 0.f};
#pragma unroll
        for (int ni = 0; ni < NI; ++ni) {
            int colL = wn0 + ni * 16 + lm;
#pragma unroll
            for (int r = 0; r < 4; ++r) {
                float v = acc[mi][ni][r] + bv4[r];
                s[r]  += v;
                s2[r] += v * v;
                CsT[(chL + r) * 65 + colL] = v;      // lanes -> consecutive colL
            }
        }
#pragma unroll
        for (int r = 0; r < 4; ++r) {
            float a = s[r], b2 = s2[r];
#pragma unroll
            for (int off = 1; off < 16; off <<= 1) {
                a  += __shfl_xor(a, off, 64);
                b2 += __shfl_xor(b2, off, 64);
            }
            if (lm == 0) {
                atomicAdd(&reds[chL + r], a);
                atomicAdd(&reds[128 + chL + r], b2);
            }
        }
    }
    __syncthreads();

    // direct transposed f32 store: out[bb][c][n0+nl] (raw, pre-BN1)
    {
        int bb = cb0 >> 13;              // COLT divides NN: no batch straddle
        int n0 = cb0 & (NN - 1);
        float* obase = out + (size_t)bb * O1 * NN + n0;
        int nl = t & 63;
#pragma unroll
        for (int it = 0; it < 32; ++it) {
            int c = it * 4 + (t >> 6);   // 0..127
            obase[(size_t)c * NN + nl] = CsT[c * 65 + nl];
        }
    }
    int recIdx = blockIdx.x & (REC1 - 1);
    atomicAdd(&partials[(size_t)recIdx * 256 + t], reds[t]);
}

// ---------------------------------------------------------------------------
// K8: in-place BN1+ReLU over out[b][c][:]. One block per (b,c) pair; each
// thread folds part1 (L2-resident, 32 KB) redundantly, then streams the row.
__global__ __launch_bounds__(256) void bn_relu_kernel(float* __restrict__ out,
                                                      const float* __restrict__ part1,
                                                      const float* __restrict__ g1,
                                                      const float* __restrict__ be1,
                                                      float invN) {
    int bid = blockIdx.x;                // 512 = 4 batches x 128 channels
    int c  = bid & 127;
    int bb = bid >> 7;

    float s = 0.f, s2 = 0.f;
#pragma unroll 8
    for (int i = 0; i < REC1; ++i) {
        s  += part1[i * 256 + c];
        s2 += part1[i * 256 + 128 + c];
    }
    float mean = s * invN;
    float var  = fmaxf(s2 * invN - mean * mean, 0.f);
    float inv  = rsqrtf(var + BN_EPS);
    float sc   = g1[c] * inv;
    float sh   = be1[c] - mean * sc;

    float4* p = (float4*)(out + (size_t)bb * O1 * NN + (size_t)c * NN);
    int t = threadIdx.x;
#pragma unroll
    for (int j = 0; j < NN / 4 / 256; ++j) {       // 8 float4 per thread
        float4 v = p[j * 256 + t];
        v.x = fmaxf(v.x * sc + sh, 0.f);
        v.y = fmaxf(v.y * sc + sh, 0.f);
        v.z = fmaxf(v.z * sc + sh, 0.f);
        v.w = fmaxf(v.w * sc + sh, 0.f);
        p[j * 256 + t] = v;
    }
}

// ---------------------------------------------------------------------------
extern "C" void kernel_launch(void* const* d_in, const int* in_sizes, int n_in,
                              void* d_out, int out_size, void* d_ws, size_t ws_size,
                              hipStream_t stream) {
    (void)in_sizes; (void)n_in; (void)out_size; (void)ws_size;

    const float* xyz1    = (const float*)d_in[0];
    const float* xyz2    = (const float*)d_in[1];
    const float* norm1   = (const float*)d_in[2];
    const float* norm2   = (const float*)d_in[3];
    const float* points1 = (const float*)d_in[4];
    const float* points2 = (const float*)d_in[5];
    const float* W0f     = (const float*)d_in[6];
    const float* b0      = (const float*)d_in[7];
    const float* g0      = (const float*)d_in[8];
    const float* be0     = (const float*)d_in[9];
    const float* W1f     = (const float*)d_in[10];
    const float* b1      = (const float*)d_in[11];
    const float* g1      = (const float*)d_in[12];
    const float* be1     = (const float*)d_in[13];
    float* out = (float*)d_out;

    // workspace carve-up (all 256B-aligned)
    char* w8 = (char*)d_ws;
    size_t off = 0;
    auto carve = [&](size_t bytes) { void* p = w8 + off; off += (bytes + 255) & ~(size_t)255; return p; };
    int*   idxW   = (int*)  carve((size_t)NCOL * 3 * sizeof(int));
    float* wW     = (float*)carve((size_t)NCOL * 3 * sizeof(float));
    u16*   p2T    = (u16*)  carve((size_t)BB * MM * C2 * 2);
    u16*   p1T    = (u16*)  carve((size_t)BB * NN * C1 * 2);
    u16*   W0b    = (u16*)  carve((size_t)O0 * CH0 * 2);
    u16*   W1b    = (u16*)  carve((size_t)O1 * O0 * 2);
    u16*   y0T    = (u16*)  carve((size_t)NCOL * O0 * 2);
    float* part0  = (float*)carve((size_t)REC0 * 512 * sizeof(float));  // 128 KB
    float* part1  = (float*)carve((size_t)REC1 * 256 * sizeof(float));  // 32 KB

    const float invN = 1.0f / (float)NCOL;

    // 2048 3-NN blocks + 6656 prep blocks + 160 zero blocks
    fused_pre_kernel<<<NB3 + PREP + ZB, 256, 0, stream>>>(
        xyz1, xyz2, norm1, norm2, idxW, wW,
        points2, p2T, points1, p1T, W0f, W0b, W1f, W1b, part0, part1);

    // GEMM0 (merged y-halves, T14 async-STAGE split)
    gemm0_kernel<<<NCOL / 64, 256, 0, stream>>>(
        W0b, p2T, p1T, idxW, wW, y0T, b0, part0);

    // GEMM1 (T14 split): raw f32 output direct to out[b][c][n]; stats to part1
    gemm1_kernel<<<NCOL / 64, 256, 0, stream>>>(
        W1b, y0T, out, b1, part0, g0, be0, invN, part1);

    // in-place BN1+ReLU (replaces the y1T round-trip finalize)
    bn_relu_kernel<<<BB * O1, 256, 0, stream>>>(out, part1, g1, be1, invN);
}